// Round 9
// baseline (213.794 us; speedup 1.0000x reference)
//
#include <hip/hip_runtime.h>
#include <hip/hip_bf16.h>
#include <stdint.h>
#include <math.h>

// PhysicsInformedAttention: B=2,N=2048,C=1024,H=16,Dh=64. fp32 I/O, int32 mask.
// R15: raise GEMM residency (both qkv+proj are phase-latency-bound at 2
//      blocks/CU — R11-R14 triangulation).
//  - qkv: BK=32, 3-buffer, counted vmcnt(4) (pipe3 recipe @ half-K).
//    LDS 48KB -> 3 blocks/CU, 12 waves/CU, 2-deep prefetch.
//  - proj: 64x64 tile, grid 1024 (16 ch x 64 tok), 2-buf BK=64, LDS 32KB ->
//    4 blocks/CU; XCD map (tb%8 == bid%8) keeps G+w panels L2-resident.
//  - flash: R14-exact (55us, proven).
// R14: fence discipline: {vmcnt -> barrier -> fence -> stage -> fence ->
//      compute} — 2nd fence pins DMA-issue before compute (R13 evidence).
// physics_bias (H,1,1): constant per softmax row -> cancels in O/l -> skipped.
// q pre-scaled by 0.125*log2e in gemm epilogue (exp2 domain, no-max softmax).

typedef __bf16 bf16;
typedef __bf16 bf16x8 __attribute__((ext_vector_type(8)));
typedef __bf16 bf16x4 __attribute__((ext_vector_type(4)));
typedef float f32x4 __attribute__((ext_vector_type(4)));
typedef float f32x16 __attribute__((ext_vector_type(16)));

#define MFMA(a,b,c) __builtin_amdgcn_mfma_f32_16x16x32_bf16((a),(b),(c),0,0,0)
#define MFMA32(a,b,c) __builtin_amdgcn_mfma_f32_32x32x16_bf16((a),(b),(c),0,0,0)
#define L2E 1.44269504f

#if __has_builtin(__builtin_amdgcn_exp2f)
#define EXP2(x) __builtin_amdgcn_exp2f(x)
#else
#define EXP2(x) exp2f(x)
#endif

#if __has_builtin(__builtin_amdgcn_sbfe)
#define SBFE1(x,o) __builtin_amdgcn_sbfe((int)(x), (int)(o), 1)
#else
#define SBFE1(x,o) (((int)(((unsigned)(x)) << (31 - (o)))) >> 31)
#endif

__device__ __forceinline__ void async16(const void* g, void* l) {
  __builtin_amdgcn_global_load_lds(
      (const __attribute__((address_space(1))) void*)g,
      (__attribute__((address_space(3))) void*)l, 16, 0, 0);
}

__device__ __forceinline__ unsigned cvt_pk_bf16(float a, float b) {
  unsigned r;
  asm("v_cvt_pk_bf16_f32 %0, %1, %2" : "=v"(r) : "v"(a), "v"(b));
  return r;
}

__device__ __forceinline__ float maskf(float p, unsigned m, int pos) {
  int sm = SBFE1(m, pos);
  return __uint_as_float(__float_as_uint(p) & (unsigned)sm);
}

// exchange: x = {a.lo-lanes, b.lo-lanes(from l-32)}, y = {a.hi-lanes(to l-32), b.hi-lanes}
__device__ __forceinline__ void lane32_swap(unsigned a, unsigned b,
                                            unsigned& x, unsigned& y, int hi) {
#if __has_builtin(__builtin_amdgcn_permlane32_swap)
  auto r = __builtin_amdgcn_permlane32_swap((int)a, (int)b, false, false);
  x = (unsigned)r[0];
  y = (unsigned)r[1];
#else
  unsigned pa_ = __shfl_xor(a, 32), pb_ = __shfl_xor(b, 32);
  x = hi ? pb_ : a;
  y = hi ? b : pa_;
#endif
}

template <bool F32>
__device__ __forceinline__ bf16x8 ld8(const void* base, size_t off) {
  if constexpr (F32) {
    const float* p = (const float*)base + off;
    float4 u = *(const float4*)p;
    float4 v = *(const float4*)(p + 4);
    bf16x8 r;
    r[0] = (bf16)u.x; r[1] = (bf16)u.y; r[2] = (bf16)u.z; r[3] = (bf16)u.w;
    r[4] = (bf16)v.x; r[5] = (bf16)v.y; r[6] = (bf16)v.z; r[7] = (bf16)v.w;
    return r;
  } else {
    return *(const bf16x8*)((const bf16*)base + off);
  }
}

// ---------------------------------------------------------------------------
// prep: blocks [0,4096): mask->bits. [4096,6144): x->bf16. [6144,7680): qkv_w.
// [7680,8192): proj_w.
__global__ __launch_bounds__(256) void prep(const int* __restrict__ mask,
                                            unsigned long long* __restrict__ mbg,
                                            const float* __restrict__ x, bf16* __restrict__ xb,
                                            const float* __restrict__ qw, bf16* __restrict__ qwb,
                                            const float* __restrict__ pw, bf16* __restrict__ pwb) {
  int bid = blockIdx.x, tid = threadIdx.x;
  if (bid < 4096) {
    int lane = tid & 63, wv = tid >> 6;
    const int* mrow = mask + (size_t)bid * 2048;
#pragma unroll
    for (int i = 0; i < 8; ++i) {
      int w = wv * 8 + i;
      unsigned long long bal = __ballot(mrow[w * 64 + lane] != 0);
      if (lane == 0) mbg[(size_t)bid * 32 + w] = bal;
    }
  } else if (bid < 6144) {
    size_t i = ((size_t)(bid - 4096) * 256 + tid) * 8;
    *(bf16x8*)&xb[i] = ld8<true>(x, i);
  } else if (bid < 7680) {
    size_t i = ((size_t)(bid - 6144) * 256 + tid) * 8;
    *(bf16x8*)&qwb[i] = ld8<true>(qw, i);
  } else {
    size_t i = ((size_t)(bid - 7680) * 256 + tid) * 8;
    *(bf16x8*)&pwb[i] = ld8<true>(pw, i);
  }
}

// ---------------------------------------------------------------------------
// qkv core: 128x128 tile, BK=32, 3-buffer counted-vmcnt pipeline, 32 phases.
// LDS/buf: A[128][64B] + B[128][64B] = 16KB; 3 bufs = 48KB -> 3 blocks/CU.
// Swizzle: 4 slots of 16B/row, slot ^= (row&3); pre-swizzled global source.
__device__ __forceinline__ void gemm_pipe32(const bf16* __restrict__ A,
                                            const bf16* __restrict__ B,
                                            int m0, int n0,
                                            f32x4 acc[4][4],
                                            char* sm) {
  const int ABYTES = 128 * 64;                        // 8KB
  const int BUF = 2 * ABYTES;                         // 16KB
  int tid = threadIdx.x, lane = tid & 63, wv = tid >> 6;
  int wm = wv & 1, wn = wv >> 1, g = lane >> 4, li = lane & 15;
  int ln4 = lane >> 2;
  int scol = ((lane & 3) << 4) ^ ((ln4 & 3) << 4);    // pre-swizzled src col

  const char* Ab = (const char*)A;
  const char* Bb = (const char*)B;

#define STAGEQ(kb, bas)                                                       \
  {                                                                           \
    _Pragma("unroll") for (int c = 0; c < 2; ++c) {                           \
      int r = wv * 32 + c * 16;                       /* wave-uniform base */ \
      async16(Ab + (size_t)(m0 + r + ln4) * 2048 + (kb) + scol,               \
              (bas) + r * 64);                                                \
      async16(Bb + (size_t)(n0 + r + ln4) * 2048 + (kb) + scol,               \
              (bas) + ABYTES + r * 64);                                       \
    }                                                                         \
  }

#define COMPQ(bas)                                                            \
  {                                                                           \
    const char* basA = (bas);                                                 \
    const char* basB = basA + ABYTES;                                         \
    bf16x8 af[4], bg[4];                                                      \
    _Pragma("unroll") for (int i = 0; i < 4; ++i) {                           \
      int rowa = wm * 64 + i * 16 + li;                                       \
      af[i] = *(const bf16x8*)(basA + rowa * 64 +                             \
                               ((g << 4) ^ ((rowa & 3) << 4)));               \
      int rowb = wn * 64 + i * 16 + li;                                       \
      bg[i] = *(const bf16x8*)(basB + rowb * 64 +                             \
                               ((g << 4) ^ ((rowb & 3) << 4)));               \
    }                                                                         \
    _Pragma("unroll") for (int i = 0; i < 4; ++i)                             \
      _Pragma("unroll") for (int j = 0; j < 4; ++j)                           \
        acc[i][j] = MFMA(af[i], bg[j], acc[i][j]);                            \
  }

  // prologue: tiles 0 and 1
  STAGEQ(0, sm);
  STAGEQ(64, sm + BUF);

  for (int p = 0; p < 31; ++p) {
    // own tile-p landed (allow tile p+1's 4 DMAs to stay in flight)
    asm volatile("s_waitcnt vmcnt(4)" ::: "memory");
    __builtin_amdgcn_s_barrier();                     // everyone's tile-p in
    __builtin_amdgcn_sched_barrier(0);
    if (p < 30) {                                     // stage p+2
      STAGEQ((p + 2) * 64, sm + ((p + 2) % 3) * BUF);
    }
    __builtin_amdgcn_sched_barrier(0);                // pin: DMA issued first
    COMPQ(sm + (p % 3) * BUF);
  }
  // peeled last phase (p=31)
  asm volatile("s_waitcnt vmcnt(0)" ::: "memory");
  __builtin_amdgcn_s_barrier();
  __builtin_amdgcn_sched_barrier(0);
  COMPQ(sm + (31 % 3) * BUF);
#undef STAGEQ
#undef COMPQ
}

// ---------------------------------------------------------------------------
// proj core: 64x64 tile, BK=64, 2-buffer pipeline, 16 phases.
// LDS/buf: A[64][128B] + B[64][128B] = 16KB; 2 bufs = 32KB -> 4 blocks/CU.
__device__ __forceinline__ void gemm_pipe64(const bf16* __restrict__ A,
                                            const bf16* __restrict__ B,
                                            int m0, int n0,
                                            f32x4 acc[2][2],
                                            char* sm) {
  const int ABYTES = 64 * 128;                        // 8KB
  const int BUF = 2 * ABYTES;                         // 16KB
  int tid = threadIdx.x, lane = tid & 63, wv = tid >> 6;
  int wm = wv & 1, wn = wv >> 1, g = lane >> 4, li = lane & 15;
  int ln8 = lane >> 3;
  int scol = ((lane & 7) << 4) ^ ((ln8 & 7) << 4);

  const char* Ab = (const char*)A;
  const char* Bb = (const char*)B;

#define STAGEP(kb, bas)                                                       \
  {                                                                           \
    _Pragma("unroll") for (int c = 0; c < 2; ++c) {                           \
      int r = wv * 16 + c * 8;                                                \
      async16(Ab + (size_t)(m0 + r + ln8) * 2048 + (kb) + scol,               \
              (bas) + r * 128);                                               \
      async16(Bb + (size_t)(n0 + r + ln8) * 2048 + (kb) + scol,               \
              (bas) + ABYTES + r * 128);                                      \
    }                                                                         \
  }

#define COMPP(bas)                                                            \
  {                                                                           \
    const char* basA = (bas);                                                 \
    const char* basB = basA + ABYTES;                                         \
    _Pragma("unroll") for (int ks = 0; ks < 2; ++ks) {                        \
      bf16x8 af[2], bg[2];                                                    \
      _Pragma("unroll") for (int i = 0; i < 2; ++i) {                         \
        int rowa = wm * 32 + i * 16 + li;                                     \
        af[i] = *(const bf16x8*)(basA + rowa * 128 +                          \
                                 ((ks * 64 + g * 16) ^ ((rowa & 7) << 4)));   \
        int rowb = wn * 32 + i * 16 + li;                                     \
        bg[i] = *(const bf16x8*)(basB + rowb * 128 +                          \
                                 ((ks * 64 + g * 16) ^ ((rowb & 7) << 4)));   \
      }                                                                       \
      _Pragma("unroll") for (int i = 0; i < 2; ++i)                           \
        _Pragma("unroll") for (int j = 0; j < 2; ++j)                         \
          acc[i][j] = MFMA(af[i], bg[j], acc[i][j]);                          \
    }                                                                         \
  }

  // prologue: tile 0 -> buf 0
  STAGEP(0, sm);

  int kt2 = 128;
  for (int p = 0; p < 16; ++p) {
    asm volatile("s_waitcnt vmcnt(0)" ::: "memory");
    __builtin_amdgcn_s_barrier();
    __builtin_amdgcn_sched_barrier(0);
    if (p < 15) {
      STAGEP(kt2, sm + ((p + 1) & 1) * BUF);
      kt2 += 128;
    }
    __builtin_amdgcn_sched_barrier(0);                // pin: DMA issued first
    COMPP(sm + (p & 1) * BUF);
  }
#undef STAGEP
#undef COMPP
}

// ---------------------------------------------------------------------------
// Legacy 2-barrier core, kept for the fp32-input fallback kernels only.
template <bool AF32, bool BF32>
__device__ __forceinline__ void gemm_core(const void* __restrict__ A,
                                          const void* __restrict__ B,
                                          int m0, int n0,
                                          f32x4 acc[4][4],
                                          bf16* Al, bf16* Bl) {
  const int K = 1024;
  int tid = threadIdx.x, lane = tid & 63, wv = tid >> 6;
  int wm = wv & 1, wn = wv >> 1, g = lane >> 4, li = lane & 15;
  int r8 = lane >> 3, c8 = lane & 7;

  for (int kt = 0; kt < K; kt += 64) {
    bf16x8 ta[4], tb[4];
#pragma unroll
    for (int i2 = 0; i2 < 4; ++i2) {
      int row = wv * 32 + i2 * 8 + r8;
      ta[i2] = ld8<AF32>(A, (size_t)(m0 + row) * K + kt + c8 * 8);
      tb[i2] = ld8<BF32>(B, (size_t)(n0 + row) * K + kt + c8 * 8);
    }
    __syncthreads();
#pragma unroll
    for (int i2 = 0; i2 < 4; ++i2) {
      int row = wv * 32 + i2 * 8 + r8;
      *(bf16x8*)&Al[row * 64 + c8 * 8] = ta[i2];
      *(bf16x8*)&Bl[row * 64 + c8 * 8] = tb[i2];
    }
    __syncthreads();
#pragma unroll
    for (int ks = 0; ks < 64; ks += 32) {
      bf16x8 af[4], bg[4];
#pragma unroll
      for (int i = 0; i < 4; ++i)
        af[i] = *(const bf16x8*)&Al[(wm * 64 + i * 16 + li) * 64 + ks + g * 8];
#pragma unroll
      for (int j = 0; j < 4; ++j)
        bg[j] = *(const bf16x8*)&Bl[(wn * 64 + j * 16 + li) * 64 + ks + g * 8];
#pragma unroll
      for (int i = 0; i < 4; ++i)
#pragma unroll
        for (int j = 0; j < 4; ++j)
          acc[i][j] = MFMA(af[i], bg[j], acc[i][j]);
    }
  }
}

// ---------------------------------------------------------------------------
__device__ __forceinline__ void epi_qk(f32x4 acc[4][4], int m0, int n0,
                                       const float* __restrict__ bias,
                                       bf16* __restrict__ qg, bf16* __restrict__ kg) {
  int lane = threadIdx.x & 63, wv = threadIdx.x >> 6;
  int wm = wv & 1, wn = wv >> 1, g = lane >> 4, li = lane & 15;
#pragma unroll
  for (int i = 0; i < 4; ++i) {
    int o = m0 + wm * 64 + i * 16 + g * 4;
    int s = o >> 10, h = (o >> 6) & 15, d = o & 63;
    float sc = s ? 1.0f : 0.125f * L2E;              // q in exp2 domain
    float b0 = bias[o], b1 = bias[o + 1], b2 = bias[o + 2], b3 = bias[o + 3];
    bf16* dstb = s ? kg : qg;
#pragma unroll
    for (int j = 0; j < 4; ++j) {
      int t = n0 + wn * 64 + j * 16 + li;
      int b = t >> 11, n = t & 2047;
      ushort4 pk;
      ((bf16*)&pk)[0] = (bf16)((acc[i][j][0] + b0) * sc);
      ((bf16*)&pk)[1] = (bf16)((acc[i][j][1] + b1) * sc);
      ((bf16*)&pk)[2] = (bf16)((acc[i][j][2] + b2) * sc);
      ((bf16*)&pk)[3] = (bf16)((acc[i][j][3] + b3) * sc);
      *(ushort4*)&dstb[(((size_t)b * 16 + h) * 2048 + n) * 64 + d] = pk;
    }
  }
}

__device__ __forceinline__ void epi_v(f32x4 acc[4][4], int m0, int n0,
                                      const float* __restrict__ bias,
                                      bf16* __restrict__ vtg) {
  int lane = threadIdx.x & 63, wvv = threadIdx.x >> 6;
  int wm = wvv & 1, wn = wvv >> 1, g = lane >> 4, li = lane & 15;
#pragma unroll
  for (int i = 0; i < 4; ++i) {
    int t = m0 + wm * 64 + i * 16 + g * 4;           // 4 consecutive tokens
    int b = t >> 11, n = t & 2047;
#pragma unroll
    for (int j = 0; j < 4; ++j) {
      int ov = n0 + wn * 64 + j * 16 + li;
      int h = ov >> 6, d = ov & 63;
      float bv = bias[ov];
      ushort4 pk;
      ((bf16*)&pk)[0] = (bf16)(acc[i][j][0] + bv);
      ((bf16*)&pk)[1] = (bf16)(acc[i][j][1] + bv);
      ((bf16*)&pk)[2] = (bf16)(acc[i][j][2] + bv);
      ((bf16*)&pk)[3] = (bf16)(acc[i][j][3] + bv);
      *(ushort4*)&vtg[(((size_t)b * 16 + h) * 64 + d) * 2048 + n] = pk;
    }
  }
}

// Fused QKV gemm (bf16 inputs): blocks [0,512) = qk, [512,768) = v.
__global__ __launch_bounds__(256, 3) void gemm_qkv(const bf16* __restrict__ xb,
                                                   const bf16* __restrict__ qwb,
                                                   const float* __restrict__ bias,
                                                   bf16* __restrict__ qg,
                                                   bf16* __restrict__ kg,
                                                   bf16* __restrict__ vtg) {
  __shared__ __align__(16) char sm[49152];           // 3 buf x (A 8K + B 8K)
  f32x4 acc[4][4];
#pragma unroll
  for (int i = 0; i < 4; ++i)
#pragma unroll
    for (int j = 0; j < 4; ++j) acc[i][j] = (f32x4){0.f, 0.f, 0.f, 0.f};
  int bid = blockIdx.x;
  if (bid < 512) {
    int m0 = (bid >> 5) * 128, n0 = (bid & 31) * 128;
    gemm_pipe32(qwb, xb, m0, n0, acc, sm);
    epi_qk(acc, m0, n0, bias, qg, kg);
  } else {
    int vb = bid - 512;
    int m0 = (vb >> 3) * 128, n0 = (vb & 7) * 128;   // m=token, n=ov
    gemm_pipe32(xb, qwb + (size_t)2048 * 1024, m0, n0, acc, sm);
    epi_v(acc, m0, n0, bias + 2048, vtg);
  }
}

// Fallback fp32-input kernels (ws too small to pre-convert)
__global__ __launch_bounds__(256) void gemm_qk_f(const float* __restrict__ x,
                                                 const float* __restrict__ w,
                                                 const float* __restrict__ bias,
                                                 bf16* __restrict__ qg,
                                                 bf16* __restrict__ kg) {
  __shared__ bf16 Al[128 * 64], Bl[128 * 64];
  f32x4 acc[4][4];
#pragma unroll
  for (int i = 0; i < 4; ++i)
#pragma unroll
    for (int j = 0; j < 4; ++j) acc[i][j] = (f32x4){0.f, 0.f, 0.f, 0.f};
  int m0 = blockIdx.y * 128, n0 = blockIdx.x * 128;
  gemm_core<true, true>(w, x, m0, n0, acc, Al, Bl);
  epi_qk(acc, m0, n0, bias, qg, kg);
}
__global__ __launch_bounds__(256) void gemm_v_f(const float* __restrict__ x,
                                                const float* __restrict__ wv_,
                                                const float* __restrict__ bias,
                                                bf16* __restrict__ vtg) {
  __shared__ bf16 Al[128 * 64], Bl[128 * 64];
  f32x4 acc[4][4];
#pragma unroll
  for (int i = 0; i < 4; ++i)
#pragma unroll
    for (int j = 0; j < 4; ++j) acc[i][j] = (f32x4){0.f, 0.f, 0.f, 0.f};
  int m0 = blockIdx.y * 128, n0 = blockIdx.x * 128;
  gemm_core<true, true>(x, wv_, m0, n0, acc, Al, Bl);
  epi_v(acc, m0, n0, bias, vtg);
}
__global__ __launch_bounds__(256) void mask_bits(const int* __restrict__ mask,
                                                 unsigned long long* __restrict__ mbg) {
  int row = blockIdx.x, lane = threadIdx.x & 63, wv = threadIdx.x >> 6;
  const int* mrow = mask + (size_t)row * 2048;
#pragma unroll
  for (int i = 0; i < 8; ++i) {
    int w = wv * 8 + i;
    unsigned long long bal = __ballot(mrow[w * 64 + lane] != 0);
    if (lane == 0) mbg[(size_t)row * 32 + w] = bal;
  }
}

// ---------------------------------------------------------------------------
// Flash attention, 32x32x16, 8 waves = 2 n-groups x 4 q-waves, async16-direct
// double-buffered K/V, one raw barrier per phase, setprio (R14-exact).
__global__ __launch_bounds__(512, 4) void flash_attn(
    const bf16* __restrict__ qg, const bf16* __restrict__ kg,
    const bf16* __restrict__ vtg, const unsigned long long* __restrict__ mbg,
    bf16* __restrict__ G) {
  // [0,64K): 2 grp x 2 buf x (K 8K | V 8K). Post-loop overlay: Ocomb = wg*8K.
  // [64K, 64K+512): lbuf.
  __shared__ __align__(16) char smem[66048];

  int tid = threadIdx.x, lane = tid & 63, wv8 = tid >> 6;
  int grp = wv8 >> 2, wg = wv8 & 3;
  int cl = lane & 31, hi = lane >> 5;
  // XCD swizzle: blk = (bh&7) + 8*(q + 16*(bh>>3)) -> xcd = bh&7; 4 heads +
  // their 16 q-blocks per XCD (K/V working set 2MB < 4MB L2).
  int sblk = blockIdx.x;
  int rest = sblk >> 3;
  int bh = ((rest >> 4) << 3) | (sblk & 7);
  int q0 = (rest & 15) * 128;
  int b = bh >> 4;

  const bf16* qbase = qg + (size_t)bh * 2048 * 64;
  const char* kgc = (const char*)(kg + (size_t)bh * 2048 * 64);
  const char* vgc = (const char*)(vtg + (size_t)bh * 64 * 2048);

  int qrow = q0 + wg * 32 + cl;
  bf16x8 qf[4];                          // Q B-frags: row q=cl, k = kd*16+hi*8
#pragma unroll
  for (int kd = 0; kd < 4; ++kd)
    qf[kd] = *(const bf16x8*)&qbase[(size_t)qrow * 64 + kd * 16 + hi * 8];

  // pre-swizzled per-lane staging source offsets (swizzle granule = 16B:
  // LDS linear slot (row, c) <- global col c^((row&7)); read undoes the XOR)
  int ln8 = lane >> 3;
  int kcol = ((lane & 7) << 4) ^ ((ln8 & 7) << 4);
  int koff = (grp * 64 + wg * 16 + ln8) * 128 + kcol;    // += 16384/phase
  int voff = (wg * 16 + ln8) * 4096 + grp * 128 + kcol;  // += 256/phase
  const char* mB = (const char*)mbg;
  unsigned moff = (unsigned)(((b * 2048 + qrow) * 32 + grp) * 8);  // += 16
  int ldsw = wg * 2048;                  // wave-uniform LDS chunk

  // prologue: stage this group's tile 0 into buf0
  {
    char* kl = smem + grp * 32768;
    char* vl = kl + 8192;
    async16(kgc + koff, kl + ldsw);
    async16(kgc + koff + 1024, kl + ldsw + 1024);
    async16(vgc + voff, vl + ldsw);
    async16(vgc + voff + 32768, vl + ldsw + 1024);
  }
  unsigned long long mw_next = *(const unsigned long long*)(mB + moff);

  f32x16 accO0, accO1;
#pragma unroll
  for (int e = 0; e < 16; ++e) { accO0[e] = 0.f; accO1[e] = 0.f; }
  float lsum = 0.f;
  int swr = (cl & 7) << 4;

  for (int t = 0; t < 16; ++t) {
    // own staging landed -> barrier -> (everyone's staging landed AND all
    // prior-phase reads of the other buffer are done)
    asm volatile("s_waitcnt vmcnt(0)" ::: "memory");
    __builtin_amdgcn_s_barrier();
    __builtin_amdgcn_sched_barrier(0);
    unsigned long long mwc = mw_next;
    if (t < 15) {                        // stage next tile into other buffer
      koff += 16384; voff += 256; moff += 16;
      char* kl = smem + grp * 32768 + (((t + 1) & 1) << 14);
      char* vl = kl + 8192;
      async16(kgc + koff, kl + ldsw);
      async16(kgc + koff + 1024, kl + ldsw + 1024);
      async16(vgc + voff, vl + ldsw);
      async16(vgc + voff + 32768, vl + ldsw + 1024);
      mw_next = *(const unsigned long long*)(mB + moff);
    }
    __builtin_amdgcn_sched_barrier(0);   // pin: DMA issued before compute
    const char* Kl = smem + grp * 32768 + ((t & 1) << 14);
    const char* Vl = Kl + 8192;

    // S^T = K Q^T (log2 domain): accS0 = n 0..31, accS1 = n 32..63
    f32x16 accS0, accS1;
#pragma unroll
    for (int e = 0; e < 16; ++e) { accS0[e] = 0.f; accS1[e] = 0.f; }
    __builtin_amdgcn_s_setprio(1);
#pragma unroll
    for (int kd = 0; kd < 4; ++kd) {
      int cb = (kd * 32 + hi * 16) ^ swr;
      bf16x8 kf0 = *(const bf16x8*)(Kl + cl * 128 + cb);
      bf16x8 kf1 = *(const bf16x8*)(Kl + (32 + cl) * 128 + cb);
      accS0 = MFMA32(kf0, qf[kd], accS0);
      accS1 = MFMA32(kf1, qf[kd], accS1);
    }
    __builtin_amdgcn_s_setprio(0);

    // p = mask * exp2(s): sbfe sign-mask + and; pack pairs via cvt_pk
    unsigned dw[16];
#pragma unroll
    for (int nb = 0; nb < 2; ++nb) {
      unsigned mql = (unsigned)(mwc >> (nb * 32));
#pragma unroll
      for (int j = 0; j < 4; ++j) {
        int pos = j * 8 + hi * 4;
        float p0 = EXP2(nb ? accS1[4 * j + 0] : accS0[4 * j + 0]);
        float p1 = EXP2(nb ? accS1[4 * j + 1] : accS0[4 * j + 1]);
        float p2 = EXP2(nb ? accS1[4 * j + 2] : accS0[4 * j + 2]);
        float p3 = EXP2(nb ? accS1[4 * j + 3] : accS0[4 * j + 3]);
        p0 = maskf(p0, mql, pos);     p1 = maskf(p1, mql, pos + 1);
        p2 = maskf(p2, mql, pos + 2); p3 = maskf(p3, mql, pos + 3);
        lsum += (p0 + p1) + (p2 + p3);
        dw[nb * 8 + 2 * j]     = cvt_pk_bf16(p0, p1);
        dw[nb * 8 + 2 * j + 1] = cvt_pk_bf16(p2, p3);
      }
    }

    // O^T += V^T P^T; B-frag assembled from own+partner dwords (lane l<->l+32)
    __builtin_amdgcn_s_setprio(1);
#pragma unroll
    for (int kk = 0; kk < 4; ++kk) {
      union { unsigned u[4]; bf16x8 v; } pa;
      lane32_swap(dw[4 * kk], dw[4 * kk + 2], pa.u[0], pa.u[2], hi);
      lane32_swap(dw[4 * kk + 1], dw[4 * kk + 3], pa.u[1], pa.u[3], hi);
      int cb = (kk * 32 + hi * 16) ^ swr;
      bf16x8 vf0 = *(const bf16x8*)(Vl + cl * 128 + cb);
      bf16x8 vf1 = *(const bf16x8*)(Vl + (32 + cl) * 128 + cb);
      accO0 = MFMA32(vf0, pa.v, accO0);
      accO1 = MFMA32(vf1, pa.v, accO1);
    }
    __builtin_amdgcn_s_setprio(0);
  }

  // partner lane (l^32) holds the other half of each q-row's p values
  float ltot = lsum + __shfl_xor(lsum, 32);

  // ---- cross-group combine (tile buffers dead -> realias) ----
  __syncthreads();
  float* oc = (float*)(smem + wg * 8192);  // [32 q][64 d] f32, XOR-swizzled
  float* lbuf = (float*)(smem + 65536);
  int osw = (cl & 7) << 4;
  if (grp == 1) {
#pragma unroll
    for (int j = 0; j < 4; ++j) {
      f32x4 qa, qb;
#pragma unroll
      for (int r = 0; r < 4; ++r) { qa[r] = accO0[4 * j + r]; qb[r] = accO1[4 * j + r]; }
      int dby = j * 32 + hi * 16;
      *(f32x4*)((char*)oc + cl * 256 + (dby ^ osw)) = qa;
      *(f32x4*)((char*)oc + cl * 256 + ((dby + 128) ^ osw)) = qb;
    }
    if (hi == 0) lbuf[wg * 32 + cl] = ltot;
  }
  __syncthreads();
  if (grp == 1) return;

  float lt2 = ltot + lbuf[wg * 32 + cl];
  float inv = 1.0f / fmaxf(lt2, 1e-37f);
#pragma unroll
  for (int j = 0; j < 4; ++j) {
    int dby = j * 32 + hi * 16;
    f32x4 qa = *(const f32x4*)((char*)oc + cl * 256 + (dby ^ osw));
    f32x4 qb = *(const f32x4*)((char*)oc + cl * 256 + ((dby + 128) ^ osw));
#pragma unroll
    for (int r = 0; r < 4; ++r) {
      accO0[4 * j + r] = (accO0[4 * j + r] + qa[r]) * inv;
      accO1[4 * j + r] = (accO1[4 * j + r] + qb[r]) * inv;
    }
  }

  // epilogue transpose, wave-private (same-wave LDS ops are in-order ->
  // overlaying the just-read oc region is safe)
  bf16* ow = (bf16*)(smem + wg * 8192);
#pragma unroll
  for (int db = 0; db < 2; ++db) {
#pragma unroll
    for (int jq = 0; jq < 4; ++jq) {
      ushort4 pk;
      ((bf16*)&pk)[0] = (bf16)(db ? accO1[4 * jq + 0] : accO0[4 * jq + 0]);
      ((bf16*)&pk)[1] = (bf16)(db ? accO1[4 * jq + 1] : accO0[4 * jq + 1]);
      ((bf16*)&pk)[2] = (bf16)(db ? accO1[4 * jq + 2] : accO0[4 * jq + 2]);
      ((bf16*)&pk)[3] = (bf16)(db ? accO1[4 * jq + 3] : accO0[4 * jq + 3]);
      int dbase = db * 32 + jq * 8 + hi * 4;
      *(ushort4*)&ow[cl * 72 + dbase] = pk;
    }
  }

  int ql = lane >> 1, part = lane & 1;
  size_t tok = (size_t)b * 2048 + q0 + wg * 32 + ql;
  bf16* dst = G + tok * 1024 + (bh & 15) * 64 + part * 32;
  const bf16* src = &ow[ql * 72 + part * 32];
#pragma unroll
  for (int j = 0; j < 4; ++j)
    *(bf16x8*)&dst[j * 8] = *(const bf16x8*)&src[j * 8];
}

// ---------------------------------------------------------------------------
// Proj (pre path): D[ch][token], 64x64 tile, grid 1024 (4 blocks/CU),
// XCD-mapped so each XCD's blocks share 8 G-panels (1MB) + all w (2MB) in L2.
__global__ __launch_bounds__(256, 4) void gemm_proj_n(const bf16* __restrict__ G,
                                                      const bf16* __restrict__ w,
                                                      const float* __restrict__ bias,
                                                      float* __restrict__ out) {
  __shared__ __align__(16) char sm[32768];           // 2 buf x (A 8K + B 8K)
  int lane = threadIdx.x & 63, wv = threadIdx.x >> 6;
  int wm = wv & 1, wn = wv >> 1, g = lane >> 4, li = lane & 15;
  // bid -> (tok-block tb in [0,64), ch-block cb in [0,16)); tb%8 == bid%8
  int bid = blockIdx.x;
  int tb = (bid & 7) + 8 * ((bid >> 3) & 7);
  int cb = bid >> 6;
  int m0 = cb * 64, n0 = tb * 64;

  f32x4 acc[2][2];
#pragma unroll
  for (int i = 0; i < 2; ++i)
#pragma unroll
    for (int j = 0; j < 2; ++j) acc[i][j] = (f32x4){0.f, 0.f, 0.f, 0.f};

  gemm_pipe64(w, G, m0, n0, acc, sm);

#pragma unroll
  for (int i = 0; i < 2; ++i) {
    int ch = m0 + wm * 32 + i * 16 + g * 4;
    float b0 = bias[ch], b1 = bias[ch + 1], b2 = bias[ch + 2], b3 = bias[ch + 3];
#pragma unroll
    for (int j = 0; j < 2; ++j) {
      int t = n0 + wn * 32 + j * 16 + li;
      float4 pk = make_float4(acc[i][j][0] + b0, acc[i][j][1] + b1,
                              acc[i][j][2] + b2, acc[i][j][3] + b3);
      *(float4*)&out[(size_t)t * 1024 + ch] = pk;
    }
  }
}

// Fallback proj (fp32 weights)
__global__ __launch_bounds__(256) void gemm_proj_f(const bf16* __restrict__ G,
                                                   const float* __restrict__ w,
                                                   const float* __restrict__ bias,
                                                   float* __restrict__ out) {
  __shared__ bf16 Al[128 * 64], Bl[128 * 64];
  f32x4 acc[4][4];
#pragma unroll
  for (int i = 0; i < 4; ++i)
#pragma unroll
    for (int j = 0; j < 4; ++j) acc[i][j] = (f32x4){0.f, 0.f, 0.f, 0.f};
  int m0 = blockIdx.y * 128, n0 = blockIdx.x * 128;
  gemm_core<true, false>(w, G, m0, n0, acc, Al, Bl);

  int lane = threadIdx.x & 63, wv = threadIdx.x >> 6;
  int wm = wv & 1, wn = wv >> 1, g = lane >> 4, li = lane & 15;
#pragma unroll
  for (int i = 0; i < 4; ++i) {
    int ch = m0 + wm * 64 + i * 16 + g * 4;
    float b0 = bias[ch], b1 = bias[ch + 1], b2 = bias[ch + 2], b3 = bias[ch + 3];
#pragma unroll
    for (int j = 0; j < 4; ++j) {
      int t = n0 + wn * 64 + j * 16 + li;
      float4 pk = make_float4(acc[i][j][0] + b0, acc[i][j][1] + b1,
                              acc[i][j][2] + b2, acc[i][j][3] + b3);
      *(float4*)&out[(size_t)t * 1024 + ch] = pk;
    }
  }
}

// ---------------------------------------------------------------------------
extern "C" void kernel_launch(void* const* d_in, const int* in_sizes, int n_in,
                              void* d_out, int out_size, void* d_ws, size_t ws_size,
                              hipStream_t stream) {
  const float* x      = (const float*)d_in[0];   // (2,2048,1024)
  const float* qkv_w  = (const float*)d_in[1];   // (3072,1024)
  const float* qkv_b  = (const float*)d_in[2];   // (3072,)
  const float* proj_w = (const float*)d_in[3];   // (1024,1024)
  const float* proj_b = (const float*)d_in[4];   // (1024,)
  // d_in[5] physics_bias: softmax-invariant, unused.
  const int* mask     = (const int*)d_in[6];     // (2,1,2048,2048) int32
  float* out = (float*)d_out;

  const size_t MB = (size_t)1 << 20;
  char* ws = (char*)d_ws;
  bf16* qg  = (bf16*)(ws);                 // 8 MB  [b][h][n][d]
  bf16* kg  = (bf16*)(ws + 8 * MB);        // 8 MB  [b][h][n][d]
  bf16* vtg = (bf16*)(ws + 16 * MB);       // 8 MB  [b][h][d][n]
  bf16* xb  = (bf16*)(ws + 24 * MB);       // 8 MB  (shared: xb dead before G written)
  bf16* G   = (bf16*)(ws + 24 * MB);       // 8 MB  [token][1024]
  unsigned long long* mbg = (unsigned long long*)(ws + 32 * MB);  // 1 MB
  bf16* qwb = (bf16*)(ws + 33 * MB);       // 6 MB
  bf16* pwb = (bf16*)(ws + 39 * MB);       // 2 MB
  bool pre = ws_size >= 41 * MB;           // constant across calls (graph-safe)

  if (pre) {
    prep<<<dim3(8192), dim3(256), 0, stream>>>(mask, mbg, x, xb, qkv_w, qwb,
                                               proj_w, pwb);
    gemm_qkv<<<dim3(768), dim3(256), 0, stream>>>(xb, qwb, qkv_b, qg, kg, vtg);
  } else {
    mask_bits<<<dim3(4096), dim3(256), 0, stream>>>(mask, mbg);
    gemm_qk_f<<<dim3(32, 16), dim3(256), 0, stream>>>(x, qkv_w, qkv_b, qg, kg);
    gemm_v_f<<<dim3(8, 32), dim3(256), 0, stream>>>(
        x, qkv_w + (size_t)2048 * 1024, qkv_b + 2048, vtg);
  }

  flash_attn<<<dim3(512), dim3(512), 0, stream>>>(qg, kg, vtg, mbg, G);

  if (pre)
    gemm_proj_n<<<dim3(1024), dim3(256), 0, stream>>>(G, pwb, proj_b, out);
  else
    gemm_proj_f<<<dim3(32, 8), dim3(256), 0, stream>>>(G, proj_w, proj_b, out);
}

// Round 10
// 208.267 us; speedup vs baseline: 1.0265x; 1.0265x over previous
//
#include <hip/hip_runtime.h>
#include <hip/hip_bf16.h>
#include <stdint.h>
#include <math.h>

// PhysicsInformedAttention: B=2,N=2048,C=1024,H=16,Dh=64. fp32 I/O, int32 mask.
// R16: R14-exact base (209.7us proven) + ONE change: XCD-aware block mapping
//      for gemm_qkv (T1). Old map spread n-panels round-robin -> each XCD L2
//      touched 12MB (>4MB) -> 54MB FETCH (4x compulsory). New map: xcd=bid&7,
//      each XCD owns 4 token-panels x 16 m-panels (4MB w + 1MB x, L2-fit);
//      v-part: one ov-panel per XCD. Bijective (8x64=512, 8x32=256).
// R15 lesson: BK=32 (32 phases) regressed — per-phase fixed cost dominates;
//      phase count is as important as residency.
// R14: fence discipline {vmcnt -> barrier -> fence -> stage -> fence ->
//      compute}; proj gemm_pipe3 (3-buf counted vmcnt(6)); flash 8w 2grpx4w
//      n-split, async16-direct dbuf, setprio, XCD swizzle.
// physics_bias (H,1,1): constant per softmax row -> cancels in O/l -> skipped.
// q pre-scaled by 0.125*log2e in gemm epilogue (exp2 domain, no-max softmax).

typedef __bf16 bf16;
typedef __bf16 bf16x8 __attribute__((ext_vector_type(8)));
typedef __bf16 bf16x4 __attribute__((ext_vector_type(4)));
typedef float f32x4 __attribute__((ext_vector_type(4)));
typedef float f32x16 __attribute__((ext_vector_type(16)));

#define MFMA(a,b,c) __builtin_amdgcn_mfma_f32_16x16x32_bf16((a),(b),(c),0,0,0)
#define MFMA32(a,b,c) __builtin_amdgcn_mfma_f32_32x32x16_bf16((a),(b),(c),0,0,0)
#define L2E 1.44269504f

#if __has_builtin(__builtin_amdgcn_exp2f)
#define EXP2(x) __builtin_amdgcn_exp2f(x)
#else
#define EXP2(x) exp2f(x)
#endif

#if __has_builtin(__builtin_amdgcn_sbfe)
#define SBFE1(x,o) __builtin_amdgcn_sbfe((int)(x), (int)(o), 1)
#else
#define SBFE1(x,o) (((int)(((unsigned)(x)) << (31 - (o)))) >> 31)
#endif

__device__ __forceinline__ void async16(const void* g, void* l) {
  __builtin_amdgcn_global_load_lds(
      (const __attribute__((address_space(1))) void*)g,
      (__attribute__((address_space(3))) void*)l, 16, 0, 0);
}

__device__ __forceinline__ unsigned cvt_pk_bf16(float a, float b) {
  unsigned r;
  asm("v_cvt_pk_bf16_f32 %0, %1, %2" : "=v"(r) : "v"(a), "v"(b));
  return r;
}

__device__ __forceinline__ float maskf(float p, unsigned m, int pos) {
  int sm = SBFE1(m, pos);
  return __uint_as_float(__float_as_uint(p) & (unsigned)sm);
}

// exchange: x = {a.lo-lanes, b.lo-lanes(from l-32)}, y = {a.hi-lanes(to l-32), b.hi-lanes}
__device__ __forceinline__ void lane32_swap(unsigned a, unsigned b,
                                            unsigned& x, unsigned& y, int hi) {
#if __has_builtin(__builtin_amdgcn_permlane32_swap)
  auto r = __builtin_amdgcn_permlane32_swap((int)a, (int)b, false, false);
  x = (unsigned)r[0];
  y = (unsigned)r[1];
#else
  unsigned pa_ = __shfl_xor(a, 32), pb_ = __shfl_xor(b, 32);
  x = hi ? pb_ : a;
  y = hi ? b : pa_;
#endif
}

template <bool F32>
__device__ __forceinline__ bf16x8 ld8(const void* base, size_t off) {
  if constexpr (F32) {
    const float* p = (const float*)base + off;
    float4 u = *(const float4*)p;
    float4 v = *(const float4*)(p + 4);
    bf16x8 r;
    r[0] = (bf16)u.x; r[1] = (bf16)u.y; r[2] = (bf16)u.z; r[3] = (bf16)u.w;
    r[4] = (bf16)v.x; r[5] = (bf16)v.y; r[6] = (bf16)v.z; r[7] = (bf16)v.w;
    return r;
  } else {
    return *(const bf16x8*)((const bf16*)base + off);
  }
}

// ---------------------------------------------------------------------------
// prep: blocks [0,4096): mask->bits. [4096,6144): x->bf16. [6144,7680): qkv_w.
// [7680,8192): proj_w.
__global__ __launch_bounds__(256) void prep(const int* __restrict__ mask,
                                            unsigned long long* __restrict__ mbg,
                                            const float* __restrict__ x, bf16* __restrict__ xb,
                                            const float* __restrict__ qw, bf16* __restrict__ qwb,
                                            const float* __restrict__ pw, bf16* __restrict__ pwb) {
  int bid = blockIdx.x, tid = threadIdx.x;
  if (bid < 4096) {
    int lane = tid & 63, wv = tid >> 6;
    const int* mrow = mask + (size_t)bid * 2048;
#pragma unroll
    for (int i = 0; i < 8; ++i) {
      int w = wv * 8 + i;
      unsigned long long bal = __ballot(mrow[w * 64 + lane] != 0);
      if (lane == 0) mbg[(size_t)bid * 32 + w] = bal;
    }
  } else if (bid < 6144) {
    size_t i = ((size_t)(bid - 4096) * 256 + tid) * 8;
    *(bf16x8*)&xb[i] = ld8<true>(x, i);
  } else if (bid < 7680) {
    size_t i = ((size_t)(bid - 6144) * 256 + tid) * 8;
    *(bf16x8*)&qwb[i] = ld8<true>(qw, i);
  } else {
    size_t i = ((size_t)(bid - 7680) * 256 + tid) * 8;
    *(bf16x8*)&pwb[i] = ld8<true>(pw, i);
  }
}

// ---------------------------------------------------------------------------
// Pipelined NT GEMM core (bf16): C[m][n] = sum_k A[m][k]*B[n][k], K=1024.
// BK=64, 2-buffer XOR-swizzled LDS, async16 with pre-swizzled global source,
// one s_barrier per phase, DMA-issue pinned before compute. BROWS = B rows.
template <int BROWS>
__device__ __forceinline__ void gemm_pipe(const bf16* __restrict__ A,
                                          const bf16* __restrict__ B,
                                          int m0, int n0,
                                          f32x4 acc[4][BROWS / 32],
                                          char* sm) {
  const int ABYTES = 128 * 128;
  const int BUF = ABYTES + BROWS * 128;
  int tid = threadIdx.x, lane = tid & 63, wv = tid >> 6;
  int wm = wv & 1, wn = wv >> 1, g = lane >> 4, li = lane & 15;
  int ln8 = lane >> 3;
  int scol = ((lane & 7) << 4) ^ ((ln8 & 7) << 4);   // pre-swizzled src col

  const char* Ab = (const char*)A;
  const char* Bb = (const char*)B;

  // prologue: stage tile 0 into buf 0
#pragma unroll
  for (int c = 0; c < 4; ++c) {
    int r = wv * 32 + c * 8;                          // wave-uniform, r%8==0
    async16(Ab + (size_t)(m0 + r + ln8) * 2048 + scol, sm + r * 128);
  }
#pragma unroll
  for (int c = 0; c < BROWS / 32; ++c) {
    int r = wv * (BROWS / 4) + c * 8;
    async16(Bb + (size_t)(n0 + r + ln8) * 2048 + scol, sm + ABYTES + r * 128);
  }

  int kt2 = 128;                                      // byte offset of next k-tile
  for (int p = 0; p < 16; ++p) {
    asm volatile("s_waitcnt vmcnt(0)" ::: "memory");  // own DMA landed
    __builtin_amdgcn_s_barrier();                     // all waves done+landed
    __builtin_amdgcn_sched_barrier(0);
    if (p < 15) {                                     // stage t+1 -> other buf
      char* bas = sm + ((p + 1) & 1) * BUF;
#pragma unroll
      for (int c = 0; c < 4; ++c) {
        int r = wv * 32 + c * 8;
        async16(Ab + (size_t)(m0 + r + ln8) * 2048 + kt2 + scol, bas + r * 128);
      }
#pragma unroll
      for (int c = 0; c < BROWS / 32; ++c) {
        int r = wv * (BROWS / 4) + c * 8;
        async16(Bb + (size_t)(n0 + r + ln8) * 2048 + kt2 + scol,
                bas + ABYTES + r * 128);
      }
      kt2 += 128;
    }
    __builtin_amdgcn_sched_barrier(0);                // pin: DMA issued first
    const char* basA = sm + (p & 1) * BUF;
    const char* basB = basA + ABYTES;
#pragma unroll
    for (int ks = 0; ks < 2; ++ks) {
      bf16x8 af[4], bg[BROWS / 32];
#pragma unroll
      for (int i = 0; i < 4; ++i) {
        int row = wm * 64 + i * 16 + li;
        af[i] = *(const bf16x8*)(basA + row * 128 +
                                 ((ks * 64 + g * 16) ^ ((row & 7) << 4)));
      }
#pragma unroll
      for (int j = 0; j < BROWS / 32; ++j) {
        int row = wn * (BROWS / 2) + j * 16 + li;
        bg[j] = *(const bf16x8*)(basB + row * 128 +
                                 ((ks * 64 + g * 16) ^ ((row & 7) << 4)));
      }
#pragma unroll
      for (int i = 0; i < 4; ++i)
#pragma unroll
        for (int j = 0; j < BROWS / 32; ++j)
          acc[i][j] = MFMA(af[i], bg[j], acc[i][j]);
    }
  }
}

// ---------------------------------------------------------------------------
// 3-buffer counted-vmcnt pipeline (T3/T4): stage tile p+2 each phase, wait
// vmcnt(6) = drain own tile-p (6 DMAs) while p+1/p+2 stay in flight.
// BROWS=64: buffer = 16K(A) + 8K(B) = 24K; 3 bufs = 72K -> 2 blocks/CU.
__device__ __forceinline__ void gemm_pipe3(const bf16* __restrict__ A,
                                           const bf16* __restrict__ B,
                                           int m0, int n0,
                                           f32x4 acc[4][2],
                                           char* sm) {
  const int ABYTES = 128 * 128;
  const int BUF = ABYTES + 64 * 128;                  // 24576
  int tid = threadIdx.x, lane = tid & 63, wv = tid >> 6;
  int wm = wv & 1, wn = wv >> 1, g = lane >> 4, li = lane & 15;
  int ln8 = lane >> 3;
  int scol = ((lane & 7) << 4) ^ ((ln8 & 7) << 4);

  const char* Ab = (const char*)A;
  const char* Bb = (const char*)B;

#define STAGE3(kb, bas)                                                       \
  {                                                                           \
    _Pragma("unroll") for (int c = 0; c < 4; ++c) {                           \
      int r = wv * 32 + c * 8;                                                \
      async16(Ab + (size_t)(m0 + r + ln8) * 2048 + (kb) + scol,               \
              (bas) + r * 128);                                               \
    }                                                                         \
    _Pragma("unroll") for (int c = 0; c < 2; ++c) {                           \
      int r = wv * 16 + c * 8;                                                \
      async16(Bb + (size_t)(n0 + r + ln8) * 2048 + (kb) + scol,               \
              (bas) + ABYTES + r * 128);                                      \
    }                                                                         \
  }

#define COMPUTE3(basAq)                                                       \
  {                                                                           \
    const char* basA = (basAq);                                               \
    const char* basB = basA + ABYTES;                                         \
    _Pragma("unroll") for (int ks = 0; ks < 2; ++ks) {                        \
      bf16x8 af[4], bg[2];                                                    \
      _Pragma("unroll") for (int i = 0; i < 4; ++i) {                         \
        int row = wm * 64 + i * 16 + li;                                      \
        af[i] = *(const bf16x8*)(basA + row * 128 +                           \
                                 ((ks * 64 + g * 16) ^ ((row & 7) << 4)));    \
      }                                                                       \
      _Pragma("unroll") for (int j = 0; j < 2; ++j) {                         \
        int row = wn * 32 + j * 16 + li;                                      \
        bg[j] = *(const bf16x8*)(basB + row * 128 +                           \
                                 ((ks * 64 + g * 16) ^ ((row & 7) << 4)));    \
      }                                                                       \
      _Pragma("unroll") for (int i = 0; i < 4; ++i)                           \
        _Pragma("unroll") for (int j = 0; j < 2; ++j)                         \
          acc[i][j] = MFMA(af[i], bg[j], acc[i][j]);                          \
    }                                                                         \
  }

  // prologue: tiles 0 and 1
  STAGE3(0, sm);
  STAGE3(128, sm + BUF);

  for (int p = 0; p < 15; ++p) {
    asm volatile("s_waitcnt vmcnt(6)" ::: "memory");  // own tile-p landed
    __builtin_amdgcn_s_barrier();                     // everyone's tile-p in
    __builtin_amdgcn_sched_barrier(0);
    if (p < 14) {                                     // stage p+2
      int b3 = (p + 2) % 3;
      STAGE3((p + 2) * 128, sm + b3 * BUF);
    }
    __builtin_amdgcn_sched_barrier(0);                // pin: DMA issued first
    COMPUTE3(sm + (p % 3) * BUF);
  }
  // peeled last phase (p=15): only tile 15 outstanding
  asm volatile("s_waitcnt vmcnt(0)" ::: "memory");
  __builtin_amdgcn_s_barrier();
  __builtin_amdgcn_sched_barrier(0);
  COMPUTE3(sm + (15 % 3) * BUF);
#undef STAGE3
#undef COMPUTE3
}

// ---------------------------------------------------------------------------
// Legacy 2-barrier core, kept for the fp32-input fallback kernels only.
template <bool AF32, bool BF32>
__device__ __forceinline__ void gemm_core(const void* __restrict__ A,
                                          const void* __restrict__ B,
                                          int m0, int n0,
                                          f32x4 acc[4][4],
                                          bf16* Al, bf16* Bl) {
  const int K = 1024;
  int tid = threadIdx.x, lane = tid & 63, wv = tid >> 6;
  int wm = wv & 1, wn = wv >> 1, g = lane >> 4, li = lane & 15;
  int r8 = lane >> 3, c8 = lane & 7;

  for (int kt = 0; kt < K; kt += 64) {
    bf16x8 ta[4], tb[4];
#pragma unroll
    for (int i2 = 0; i2 < 4; ++i2) {
      int row = wv * 32 + i2 * 8 + r8;
      ta[i2] = ld8<AF32>(A, (size_t)(m0 + row) * K + kt + c8 * 8);
      tb[i2] = ld8<BF32>(B, (size_t)(n0 + row) * K + kt + c8 * 8);
    }
    __syncthreads();
#pragma unroll
    for (int i2 = 0; i2 < 4; ++i2) {
      int row = wv * 32 + i2 * 8 + r8;
      *(bf16x8*)&Al[row * 64 + c8 * 8] = ta[i2];
      *(bf16x8*)&Bl[row * 64 + c8 * 8] = tb[i2];
    }
    __syncthreads();
#pragma unroll
    for (int ks = 0; ks < 64; ks += 32) {
      bf16x8 af[4], bg[4];
#pragma unroll
      for (int i = 0; i < 4; ++i)
        af[i] = *(const bf16x8*)&Al[(wm * 64 + i * 16 + li) * 64 + ks + g * 8];
#pragma unroll
      for (int j = 0; j < 4; ++j)
        bg[j] = *(const bf16x8*)&Bl[(wn * 64 + j * 16 + li) * 64 + ks + g * 8];
#pragma unroll
      for (int i = 0; i < 4; ++i)
#pragma unroll
        for (int j = 0; j < 4; ++j)
          acc[i][j] = MFMA(af[i], bg[j], acc[i][j]);
    }
  }
}

// ---------------------------------------------------------------------------
__device__ __forceinline__ void epi_qk(f32x4 acc[4][4], int m0, int n0,
                                       const float* __restrict__ bias,
                                       bf16* __restrict__ qg, bf16* __restrict__ kg) {
  int lane = threadIdx.x & 63, wv = threadIdx.x >> 6;
  int wm = wv & 1, wn = wv >> 1, g = lane >> 4, li = lane & 15;
#pragma unroll
  for (int i = 0; i < 4; ++i) {
    int o = m0 + wm * 64 + i * 16 + g * 4;
    int s = o >> 10, h = (o >> 6) & 15, d = o & 63;
    float sc = s ? 1.0f : 0.125f * L2E;              // q in exp2 domain
    float b0 = bias[o], b1 = bias[o + 1], b2 = bias[o + 2], b3 = bias[o + 3];
    bf16* dstb = s ? kg : qg;
#pragma unroll
    for (int j = 0; j < 4; ++j) {
      int t = n0 + wn * 64 + j * 16 + li;
      int b = t >> 11, n = t & 2047;
      ushort4 pk;
      ((bf16*)&pk)[0] = (bf16)((acc[i][j][0] + b0) * sc);
      ((bf16*)&pk)[1] = (bf16)((acc[i][j][1] + b1) * sc);
      ((bf16*)&pk)[2] = (bf16)((acc[i][j][2] + b2) * sc);
      ((bf16*)&pk)[3] = (bf16)((acc[i][j][3] + b3) * sc);
      *(ushort4*)&dstb[(((size_t)b * 16 + h) * 2048 + n) * 64 + d] = pk;
    }
  }
}

__device__ __forceinline__ void epi_v(f32x4 acc[4][4], int m0, int n0,
                                      const float* __restrict__ bias,
                                      bf16* __restrict__ vtg) {
  int lane = threadIdx.x & 63, wvv = threadIdx.x >> 6;
  int wm = wvv & 1, wn = wvv >> 1, g = lane >> 4, li = lane & 15;
#pragma unroll
  for (int i = 0; i < 4; ++i) {
    int t = m0 + wm * 64 + i * 16 + g * 4;           // 4 consecutive tokens
    int b = t >> 11, n = t & 2047;
#pragma unroll
    for (int j = 0; j < 4; ++j) {
      int ov = n0 + wn * 64 + j * 16 + li;
      int h = ov >> 6, d = ov & 63;
      float bv = bias[ov];
      ushort4 pk;
      ((bf16*)&pk)[0] = (bf16)(acc[i][j][0] + bv);
      ((bf16*)&pk)[1] = (bf16)(acc[i][j][1] + bv);
      ((bf16*)&pk)[2] = (bf16)(acc[i][j][2] + bv);
      ((bf16*)&pk)[3] = (bf16)(acc[i][j][3] + bv);
      *(ushort4*)&vtg[(((size_t)b * 16 + h) * 64 + d) * 2048 + n] = pk;
    }
  }
}

// Fused QKV gemm (bf16 inputs): blocks [0,512) = qk, [512,768) = v.
// R16 XCD map: qk: xcd=bid&7 owns n-panels [xcd*4, xcd*4+4) x all 16 m-panels
// (L2 set: 4MB w + 1MB x). v: one ov-panel per XCD.
__global__ __launch_bounds__(256) void gemm_qkv(const bf16* __restrict__ xb,
                                                const bf16* __restrict__ qwb,
                                                const float* __restrict__ bias,
                                                bf16* __restrict__ qg,
                                                bf16* __restrict__ kg,
                                                bf16* __restrict__ vtg) {
  __shared__ __align__(16) char sm[65536];           // 2 buf x (A 16K + B 16K)
  f32x4 acc[4][4];
#pragma unroll
  for (int i = 0; i < 4; ++i)
#pragma unroll
    for (int j = 0; j < 4; ++j) acc[i][j] = (f32x4){0.f, 0.f, 0.f, 0.f};
  int bid = blockIdx.x;
  if (bid < 512) {
    int xcd = bid & 7, local = bid >> 3;             // local in [0,64)
    int m0 = (local >> 2) * 128;                     // 16 m-panels
    int n0 = (xcd * 4 + (local & 3)) * 128;          // 32 n-panels, 4/XCD
    gemm_pipe<128>(qwb, xb, m0, n0, acc, sm);
    epi_qk(acc, m0, n0, bias, qg, kg);
  } else {
    int vb = bid - 512;
    int xcd = vb & 7, local = vb >> 3;               // local in [0,32)
    int m0 = local * 128;                            // 32 token-panels
    int n0 = xcd * 128;                              // 8 ov-panels, 1/XCD
    gemm_pipe<128>(xb, qwb + (size_t)2048 * 1024, m0, n0, acc, sm);
    epi_v(acc, m0, n0, bias + 2048, vtg);
  }
}

// Fallback fp32-input kernels (ws too small to pre-convert)
__global__ __launch_bounds__(256) void gemm_qk_f(const float* __restrict__ x,
                                                 const float* __restrict__ w,
                                                 const float* __restrict__ bias,
                                                 bf16* __restrict__ qg,
                                                 bf16* __restrict__ kg) {
  __shared__ bf16 Al[128 * 64], Bl[128 * 64];
  f32x4 acc[4][4];
#pragma unroll
  for (int i = 0; i < 4; ++i)
#pragma unroll
    for (int j = 0; j < 4; ++j) acc[i][j] = (f32x4){0.f, 0.f, 0.f, 0.f};
  int m0 = blockIdx.y * 128, n0 = blockIdx.x * 128;
  gemm_core<true, true>(w, x, m0, n0, acc, Al, Bl);
  epi_qk(acc, m0, n0, bias, qg, kg);
}
__global__ __launch_bounds__(256) void gemm_v_f(const float* __restrict__ x,
                                                const float* __restrict__ wv_,
                                                const float* __restrict__ bias,
                                                bf16* __restrict__ vtg) {
  __shared__ bf16 Al[128 * 64], Bl[128 * 64];
  f32x4 acc[4][4];
#pragma unroll
  for (int i = 0; i < 4; ++i)
#pragma unroll
    for (int j = 0; j < 4; ++j) acc[i][j] = (f32x4){0.f, 0.f, 0.f, 0.f};
  int m0 = blockIdx.y * 128, n0 = blockIdx.x * 128;
  gemm_core<true, true>(x, wv_, m0, n0, acc, Al, Bl);
  epi_v(acc, m0, n0, bias, vtg);
}
__global__ __launch_bounds__(256) void mask_bits(const int* __restrict__ mask,
                                                 unsigned long long* __restrict__ mbg) {
  int row = blockIdx.x, lane = threadIdx.x & 63, wv = threadIdx.x >> 6;
  const int* mrow = mask + (size_t)row * 2048;
#pragma unroll
  for (int i = 0; i < 8; ++i) {
    int w = wv * 8 + i;
    unsigned long long bal = __ballot(mrow[w * 64 + lane] != 0);
    if (lane == 0) mbg[(size_t)row * 32 + w] = bal;
  }
}

// ---------------------------------------------------------------------------
// Flash attention, 32x32x16, 8 waves = 2 n-groups x 4 q-waves, async16-direct
// double-buffered K/V, one raw barrier per phase, setprio (R14-exact).
__global__ __launch_bounds__(512, 4) void flash_attn(
    const bf16* __restrict__ qg, const bf16* __restrict__ kg,
    const bf16* __restrict__ vtg, const unsigned long long* __restrict__ mbg,
    bf16* __restrict__ G) {
  // [0,64K): 2 grp x 2 buf x (K 8K | V 8K). Post-loop overlay: Ocomb = wg*8K.
  // [64K, 64K+512): lbuf.
  __shared__ __align__(16) char smem[66048];

  int tid = threadIdx.x, lane = tid & 63, wv8 = tid >> 6;
  int grp = wv8 >> 2, wg = wv8 & 3;
  int cl = lane & 31, hi = lane >> 5;
  // XCD swizzle: blk = (bh&7) + 8*(q + 16*(bh>>3)) -> xcd = bh&7; 4 heads +
  // their 16 q-blocks per XCD (K/V working set 2MB < 4MB L2).
  int sblk = blockIdx.x;
  int rest = sblk >> 3;
  int bh = ((rest >> 4) << 3) | (sblk & 7);
  int q0 = (rest & 15) * 128;
  int b = bh >> 4;

  const bf16* qbase = qg + (size_t)bh * 2048 * 64;
  const char* kgc = (const char*)(kg + (size_t)bh * 2048 * 64);
  const char* vgc = (const char*)(vtg + (size_t)bh * 64 * 2048);

  int qrow = q0 + wg * 32 + cl;
  bf16x8 qf[4];                          // Q B-frags: row q=cl, k = kd*16+hi*8
#pragma unroll
  for (int kd = 0; kd < 4; ++kd)
    qf[kd] = *(const bf16x8*)&qbase[(size_t)qrow * 64 + kd * 16 + hi * 8];

  // pre-swizzled per-lane staging source offsets (swizzle granule = 16B:
  // LDS linear slot (row, c) <- global col c^((row&7)); read undoes the XOR)
  int ln8 = lane >> 3;
  int kcol = ((lane & 7) << 4) ^ ((ln8 & 7) << 4);
  int koff = (grp * 64 + wg * 16 + ln8) * 128 + kcol;    // += 16384/phase
  int voff = (wg * 16 + ln8) * 4096 + grp * 128 + kcol;  // += 256/phase
  const char* mB = (const char*)mbg;
  unsigned moff = (unsigned)(((b * 2048 + qrow) * 32 + grp) * 8);  // += 16
  int ldsw = wg * 2048;                  // wave-uniform LDS chunk

  // prologue: stage this group's tile 0 into buf0
  {
    char* kl = smem + grp * 32768;
    char* vl = kl + 8192;
    async16(kgc + koff, kl + ldsw);
    async16(kgc + koff + 1024, kl + ldsw + 1024);
    async16(vgc + voff, vl + ldsw);
    async16(vgc + voff + 32768, vl + ldsw + 1024);
  }
  unsigned long long mw_next = *(const unsigned long long*)(mB + moff);

  f32x16 accO0, accO1;
#pragma unroll
  for (int e = 0; e < 16; ++e) { accO0[e] = 0.f; accO1[e] = 0.f; }
  float lsum = 0.f;
  int swr = (cl & 7) << 4;

  for (int t = 0; t < 16; ++t) {
    // own staging landed -> barrier -> (everyone's staging landed AND all
    // prior-phase reads of the other buffer are done)
    asm volatile("s_waitcnt vmcnt(0)" ::: "memory");
    __builtin_amdgcn_s_barrier();
    __builtin_amdgcn_sched_barrier(0);
    unsigned long long mwc = mw_next;
    if (t < 15) {                        // stage next tile into other buffer
      koff += 16384; voff += 256; moff += 16;
      char* kl = smem + grp * 32768 + (((t + 1) & 1) << 14);
      char* vl = kl + 8192;
      async16(kgc + koff, kl + ldsw);
      async16(kgc + koff + 1024, kl + ldsw + 1024);
      async16(vgc + voff, vl + ldsw);
      async16(vgc + voff + 32768, vl + ldsw + 1024);
      mw_next = *(const unsigned long long*)(mB + moff);
    }
    __builtin_amdgcn_sched_barrier(0);   // pin: DMA issued before compute
    const char* Kl = smem + grp * 32768 + ((t & 1) << 14);
    const char* Vl = Kl + 8192;

    // S^T = K Q^T (log2 domain): accS0 = n 0..31, accS1 = n 32..63
    f32x16 accS0, accS1;
#pragma unroll
    for (int e = 0; e < 16; ++e) { accS0[e] = 0.f; accS1[e] = 0.f; }
    __builtin_amdgcn_s_setprio(1);
#pragma unroll
    for (int kd = 0; kd < 4; ++kd) {
      int cb = (kd * 32 + hi * 16) ^ swr;
      bf16x8 kf0 = *(const bf16x8*)(Kl + cl * 128 + cb);
      bf16x8 kf1 = *(const bf16x8*)(Kl + (32 + cl) * 128 + cb);
      accS0 = MFMA32(kf0, qf[kd], accS0);
      accS1 = MFMA32(kf1, qf[kd], accS1);
    }
    __builtin_amdgcn_s_setprio(0);

    // p = mask * exp2(s): sbfe sign-mask + and; pack pairs via cvt_pk
    unsigned dw[16];
#pragma unroll
    for (int nb = 0; nb < 2; ++nb) {
      unsigned mql = (unsigned)(mwc >> (nb * 32));
#pragma unroll
      for (int j = 0; j < 4; ++j) {
        int pos = j * 8 + hi * 4;
        float p0 = EXP2(nb ? accS1[4 * j + 0] : accS0[4 * j + 0]);
        float p1 = EXP2(nb ? accS1[4 * j + 1] : accS0[4 * j + 1]);
        float p2 = EXP2(nb ? accS1[4 * j + 2] : accS0[4 * j + 2]);
        float p3 = EXP2(nb ? accS1[4 * j + 3] : accS0[4 * j + 3]);
        p0 = maskf(p0, mql, pos);     p1 = maskf(p1, mql, pos + 1);
        p2 = maskf(p2, mql, pos + 2); p3 = maskf(p3, mql, pos + 3);
        lsum += (p0 + p1) + (p2 + p3);
        dw[nb * 8 + 2 * j]     = cvt_pk_bf16(p0, p1);
        dw[nb * 8 + 2 * j + 1] = cvt_pk_bf16(p2, p3);
      }
    }

    // O^T += V^T P^T; B-frag assembled from own+partner dwords (lane l<->l+32)
    __builtin_amdgcn_s_setprio(1);
#pragma unroll
    for (int kk = 0; kk < 4; ++kk) {
      union { unsigned u[4]; bf16x8 v; } pa;
      lane32_swap(dw[4 * kk], dw[4 * kk + 2], pa.u[0], pa.u[2], hi);
      lane32_swap(dw[4 * kk + 1], dw[4 * kk + 3], pa.u[1], pa.u[3], hi);
      int cb = (kk * 32 + hi * 16) ^ swr;
      bf16x8 vf0 = *(const bf16x8*)(Vl + cl * 128 + cb);
      bf16x8 vf1 = *(const bf16x8*)(Vl + (32 + cl) * 128 + cb);
      accO0 = MFMA32(vf0, pa.v, accO0);
      accO1 = MFMA32(vf1, pa.v, accO1);
    }
    __builtin_amdgcn_s_setprio(0);
  }

  // partner lane (l^32) holds the other half of each q-row's p values
  float ltot = lsum + __shfl_xor(lsum, 32);

  // ---- cross-group combine (tile buffers dead -> realias) ----
  __syncthreads();
  float* oc = (float*)(smem + wg * 8192);  // [32 q][64 d] f32, XOR-swizzled
  float* lbuf = (float*)(smem + 65536);
  int osw = (cl & 7) << 4;
  if (grp == 1) {
#pragma unroll
    for (int j = 0; j < 4; ++j) {
      f32x4 qa, qb;
#pragma unroll
      for (int r = 0; r < 4; ++r) { qa[r] = accO0[4 * j + r]; qb[r] = accO1[4 * j + r]; }
      int dby = j * 32 + hi * 16;
      *(f32x4*)((char*)oc + cl * 256 + (dby ^ osw)) = qa;
      *(f32x4*)((char*)oc + cl * 256 + ((dby + 128) ^ osw)) = qb;
    }
    if (hi == 0) lbuf[wg * 32 + cl] = ltot;
  }
  __syncthreads();
  if (grp == 1) return;

  float lt2 = ltot + lbuf[wg * 32 + cl];
  float inv = 1.0f / fmaxf(lt2, 1e-37f);
#pragma unroll
  for (int j = 0; j < 4; ++j) {
    int dby = j * 32 + hi * 16;
    f32x4 qa = *(const f32x4*)((char*)oc + cl * 256 + (dby ^ osw));
    f32x4 qb = *(const f32x4*)((char*)oc + cl * 256 + ((dby + 128) ^ osw));
#pragma unroll
    for (int r = 0; r < 4; ++r) {
      accO0[4 * j + r] = (accO0[4 * j + r] + qa[r]) * inv;
      accO1[4 * j + r] = (accO1[4 * j + r] + qb[r]) * inv;
    }
  }

  // epilogue transpose, wave-private (same-wave LDS ops are in-order ->
  // overlaying the just-read oc region is safe)
  bf16* ow = (bf16*)(smem + wg * 8192);
#pragma unroll
  for (int db = 0; db < 2; ++db) {
#pragma unroll
    for (int jq = 0; jq < 4; ++jq) {
      ushort4 pk;
      ((bf16*)&pk)[0] = (bf16)(db ? accO1[4 * jq + 0] : accO0[4 * jq + 0]);
      ((bf16*)&pk)[1] = (bf16)(db ? accO1[4 * jq + 1] : accO0[4 * jq + 1]);
      ((bf16*)&pk)[2] = (bf16)(db ? accO1[4 * jq + 2] : accO0[4 * jq + 2]);
      ((bf16*)&pk)[3] = (bf16)(db ? accO1[4 * jq + 3] : accO0[4 * jq + 3]);
      int dbase = db * 32 + jq * 8 + hi * 4;
      *(ushort4*)&ow[cl * 72 + dbase] = pk;
    }
  }

  int ql = lane >> 1, part = lane & 1;
  size_t tok = (size_t)b * 2048 + q0 + wg * 32 + ql;
  bf16* dst = G + tok * 1024 + (bh & 15) * 64 + part * 32;
  const bf16* src = &ow[ql * 72 + part * 32];
#pragma unroll
  for (int j = 0; j < 4; ++j)
    *(bf16x8*)&dst[j * 8] = *(const bf16x8*)&src[j * 8];
}

// ---------------------------------------------------------------------------
// Proj (pre path): D[ch][token], tile 128x64, 3-buffer counted-vmcnt pipeline.
__global__ __launch_bounds__(256) void gemm_proj_n(const bf16* __restrict__ G,
                                                   const bf16* __restrict__ w,
                                                   const float* __restrict__ bias,
                                                   float* __restrict__ out) {
  __shared__ __align__(16) char sm[73728];           // 3 buf x (A 16K + B 8K)
  int lane = threadIdx.x & 63, wv = threadIdx.x >> 6;
  int wm = wv & 1, wn = wv >> 1, g = lane >> 4, li = lane & 15;
  int m0 = blockIdx.y * 128, n0 = blockIdx.x * 64;

  f32x4 acc[4][2];
#pragma unroll
  for (int i = 0; i < 4; ++i)
#pragma unroll
    for (int j = 0; j < 2; ++j) acc[i][j] = (f32x4){0.f, 0.f, 0.f, 0.f};

  gemm_pipe3(w, G, m0, n0, acc, sm);

#pragma unroll
  for (int i = 0; i < 4; ++i) {
    int ch = m0 + wm * 64 + i * 16 + g * 4;
    float b0 = bias[ch], b1 = bias[ch + 1], b2 = bias[ch + 2], b3 = bias[ch + 3];
#pragma unroll
    for (int j = 0; j < 2; ++j) {
      int t = n0 + wn * 32 + j * 16 + li;
      float4 pk = make_float4(acc[i][j][0] + b0, acc[i][j][1] + b1,
                              acc[i][j][2] + b2, acc[i][j][3] + b3);
      *(float4*)&out[(size_t)t * 1024 + ch] = pk;
    }
  }
}

// Fallback proj (fp32 weights)
__global__ __launch_bounds__(256) void gemm_proj_f(const bf16* __restrict__ G,
                                                   const float* __restrict__ w,
                                                   const float* __restrict__ bias,
                                                   float* __restrict__ out) {
  __shared__ bf16 Al[128 * 64], Bl[128 * 64];
  f32x4 acc[4][4];
#pragma unroll
  for (int i = 0; i < 4; ++i)
#pragma unroll
    for (int j = 0; j < 4; ++j) acc[i][j] = (f32x4){0.f, 0.f, 0.f, 0.f};
  int m0 = blockIdx.y * 128, n0 = blockIdx.x * 128;
  gemm_core<true, false>(w, G, m0, n0, acc, Al, Bl);

  int lane = threadIdx.x & 63, wv = threadIdx.x >> 6;
  int wm = wv & 1, wn = wv >> 1, g = lane >> 4, li = lane & 15;
#pragma unroll
  for (int i = 0; i < 4; ++i) {
    int ch = m0 + wm * 64 + i * 16 + g * 4;
    float b0 = bias[ch], b1 = bias[ch + 1], b2 = bias[ch + 2], b3 = bias[ch + 3];
#pragma unroll
    for (int j = 0; j < 4; ++j) {
      int t = n0 + wn * 64 + j * 16 + li;
      float4 pk = make_float4(acc[i][j][0] + b0, acc[i][j][1] + b1,
                              acc[i][j][2] + b2, acc[i][j][3] + b3);
      *(float4*)&out[(size_t)t * 1024 + ch] = pk;
    }
  }
}

// ---------------------------------------------------------------------------
extern "C" void kernel_launch(void* const* d_in, const int* in_sizes, int n_in,
                              void* d_out, int out_size, void* d_ws, size_t ws_size,
                              hipStream_t stream) {
  const float* x      = (const float*)d_in[0];   // (2,2048,1024)
  const float* qkv_w  = (const float*)d_in[1];   // (3072,1024)
  const float* qkv_b  = (const float*)d_in[2];   // (3072,)
  const float* proj_w = (const float*)d_in[3];   // (1024,1024)
  const float* proj_b = (const float*)d_in[4];   // (1024,)
  // d_in[5] physics_bias: softmax-invariant, unused.
  const int* mask     = (const int*)d_in[6];     // (2,1,2048,2048) int32
  float* out = (float*)d_out;

  const size_t MB = (size_t)1 << 20;
  char* ws = (char*)d_ws;
  bf16* qg  = (bf16*)(ws);                 // 8 MB  [b][h][n][d]
  bf16* kg  = (bf16*)(ws + 8 * MB);        // 8 MB  [b][h][n][d]
  bf16* vtg = (bf16*)(ws + 16 * MB);       // 8 MB  [b][h][d][n]
  bf16* xb  = (bf16*)(ws + 24 * MB);       // 8 MB  (shared: xb dead before G written)
  bf16* G   = (bf16*)(ws + 24 * MB);       // 8 MB  [token][1024]
  unsigned long long* mbg = (unsigned long long*)(ws + 32 * MB);  // 1 MB
  bf16* qwb = (bf16*)(ws + 33 * MB);       // 6 MB
  bf16* pwb = (bf16*)(ws + 39 * MB);       // 2 MB
  bool pre = ws_size >= 41 * MB;           // constant across calls (graph-safe)

  if (pre) {
    prep<<<dim3(8192), dim3(256), 0, stream>>>(mask, mbg, x, xb, qkv_w, qwb,
                                               proj_w, pwb);
    gemm_qkv<<<dim3(768), dim3(256), 0, stream>>>(xb, qwb, qkv_b, qg, kg, vtg);
  } else {
    mask_bits<<<dim3(4096), dim3(256), 0, stream>>>(mask, mbg);
    gemm_qk_f<<<dim3(32, 16), dim3(256), 0, stream>>>(x, qkv_w, qkv_b, qg, kg);
    gemm_v_f<<<dim3(8, 32), dim3(256), 0, stream>>>(
        x, qkv_w + (size_t)2048 * 1024, qkv_b + 2048, vtg);
  }

  flash_attn<<<dim3(512), dim3(512), 0, stream>>>(qg, kg, vtg, mbg, G);

  if (pre)
    gemm_proj_n<<<dim3(64, 8), dim3(256), 0, stream>>>(G, pwb, proj_b, out);
  else
    gemm_proj_f<<<dim3(32, 8), dim3(256), 0, stream>>>(G, proj_w, proj_b, out);
}

// Round 11
// 202.219 us; speedup vs baseline: 1.0572x; 1.0299x over previous
//
#include <hip/hip_runtime.h>
#include <hip/hip_bf16.h>
#include <stdint.h>
#include <math.h>

// PhysicsInformedAttention: B=2,N=2048,C=1024,H=16,Dh=64. fp32 I/O, int32 mask.
// R17: (1) qkv tail fix: v-part split into 512 half-tiles (128tok x 64ov,
//      gemm_pipe<64>) -> grid 1024; backfill window [T,1.5T] runs full-width
//      instead of 256 blocks on a half-empty machine (makespan 2T -> 1.5T).
//      v XCD map: each XCD owns 4 token-panels x all 16 ov-panels (1MB xb +
//      2MB wv = 3MB < 4MB L2; old map streamed all 8MB xb per XCD).
//      (2) flash: persistent zero16 C-operand for the first MFMA of each
//      accS chain (D!=C) -> removes 32 per-phase zero-init VALU ops.
// R16: qk XCD map (xcd=bid&7 owns 4 token-panels x 16 m-panels).
// R15 lesson: phase count matters as much as residency (BK=32 regressed).
// R14: fence discipline {vmcnt -> barrier -> fence -> stage -> fence ->
//      compute}; proj gemm_pipe3 (3-buf counted vmcnt(6)); flash 8w 2grpx4w
//      n-split, async16-direct dbuf, setprio, XCD swizzle.
// physics_bias (H,1,1): constant per softmax row -> cancels in O/l -> skipped.
// q pre-scaled by 0.125*log2e in gemm epilogue (exp2 domain, no-max softmax).

typedef __bf16 bf16;
typedef __bf16 bf16x8 __attribute__((ext_vector_type(8)));
typedef __bf16 bf16x4 __attribute__((ext_vector_type(4)));
typedef float f32x4 __attribute__((ext_vector_type(4)));
typedef float f32x16 __attribute__((ext_vector_type(16)));

#define MFMA(a,b,c) __builtin_amdgcn_mfma_f32_16x16x32_bf16((a),(b),(c),0,0,0)
#define MFMA32(a,b,c) __builtin_amdgcn_mfma_f32_32x32x16_bf16((a),(b),(c),0,0,0)
#define L2E 1.44269504f

#if __has_builtin(__builtin_amdgcn_exp2f)
#define EXP2(x) __builtin_amdgcn_exp2f(x)
#else
#define EXP2(x) exp2f(x)
#endif

#if __has_builtin(__builtin_amdgcn_sbfe)
#define SBFE1(x,o) __builtin_amdgcn_sbfe((int)(x), (int)(o), 1)
#else
#define SBFE1(x,o) (((int)(((unsigned)(x)) << (31 - (o)))) >> 31)
#endif

__device__ __forceinline__ void async16(const void* g, void* l) {
  __builtin_amdgcn_global_load_lds(
      (const __attribute__((address_space(1))) void*)g,
      (__attribute__((address_space(3))) void*)l, 16, 0, 0);
}

__device__ __forceinline__ unsigned cvt_pk_bf16(float a, float b) {
  unsigned r;
  asm("v_cvt_pk_bf16_f32 %0, %1, %2" : "=v"(r) : "v"(a), "v"(b));
  return r;
}

__device__ __forceinline__ float maskf(float p, unsigned m, int pos) {
  int sm = SBFE1(m, pos);
  return __uint_as_float(__float_as_uint(p) & (unsigned)sm);
}

// exchange: x = {a.lo-lanes, b.lo-lanes(from l-32)}, y = {a.hi-lanes(to l-32), b.hi-lanes}
__device__ __forceinline__ void lane32_swap(unsigned a, unsigned b,
                                            unsigned& x, unsigned& y, int hi) {
#if __has_builtin(__builtin_amdgcn_permlane32_swap)
  auto r = __builtin_amdgcn_permlane32_swap((int)a, (int)b, false, false);
  x = (unsigned)r[0];
  y = (unsigned)r[1];
#else
  unsigned pa_ = __shfl_xor(a, 32), pb_ = __shfl_xor(b, 32);
  x = hi ? pb_ : a;
  y = hi ? b : pa_;
#endif
}

template <bool F32>
__device__ __forceinline__ bf16x8 ld8(const void* base, size_t off) {
  if constexpr (F32) {
    const float* p = (const float*)base + off;
    float4 u = *(const float4*)p;
    float4 v = *(const float4*)(p + 4);
    bf16x8 r;
    r[0] = (bf16)u.x; r[1] = (bf16)u.y; r[2] = (bf16)u.z; r[3] = (bf16)u.w;
    r[4] = (bf16)v.x; r[5] = (bf16)v.y; r[6] = (bf16)v.z; r[7] = (bf16)v.w;
    return r;
  } else {
    return *(const bf16x8*)((const bf16*)base + off);
  }
}

// ---------------------------------------------------------------------------
// prep: blocks [0,4096): mask->bits. [4096,6144): x->bf16. [6144,7680): qkv_w.
// [7680,8192): proj_w.
__global__ __launch_bounds__(256) void prep(const int* __restrict__ mask,
                                            unsigned long long* __restrict__ mbg,
                                            const float* __restrict__ x, bf16* __restrict__ xb,
                                            const float* __restrict__ qw, bf16* __restrict__ qwb,
                                            const float* __restrict__ pw, bf16* __restrict__ pwb) {
  int bid = blockIdx.x, tid = threadIdx.x;
  if (bid < 4096) {
    int lane = tid & 63, wv = tid >> 6;
    const int* mrow = mask + (size_t)bid * 2048;
#pragma unroll
    for (int i = 0; i < 8; ++i) {
      int w = wv * 8 + i;
      unsigned long long bal = __ballot(mrow[w * 64 + lane] != 0);
      if (lane == 0) mbg[(size_t)bid * 32 + w] = bal;
    }
  } else if (bid < 6144) {
    size_t i = ((size_t)(bid - 4096) * 256 + tid) * 8;
    *(bf16x8*)&xb[i] = ld8<true>(x, i);
  } else if (bid < 7680) {
    size_t i = ((size_t)(bid - 6144) * 256 + tid) * 8;
    *(bf16x8*)&qwb[i] = ld8<true>(qw, i);
  } else {
    size_t i = ((size_t)(bid - 7680) * 256 + tid) * 8;
    *(bf16x8*)&pwb[i] = ld8<true>(pw, i);
  }
}

// ---------------------------------------------------------------------------
// Pipelined NT GEMM core (bf16): C[m][n] = sum_k A[m][k]*B[n][k], K=1024.
// BK=64, 2-buffer XOR-swizzled LDS, async16 with pre-swizzled global source,
// one s_barrier per phase, DMA-issue pinned before compute. BROWS = B rows.
template <int BROWS>
__device__ __forceinline__ void gemm_pipe(const bf16* __restrict__ A,
                                          const bf16* __restrict__ B,
                                          int m0, int n0,
                                          f32x4 acc[4][BROWS / 32],
                                          char* sm) {
  const int ABYTES = 128 * 128;
  const int BUF = ABYTES + BROWS * 128;
  int tid = threadIdx.x, lane = tid & 63, wv = tid >> 6;
  int wm = wv & 1, wn = wv >> 1, g = lane >> 4, li = lane & 15;
  int ln8 = lane >> 3;
  int scol = ((lane & 7) << 4) ^ ((ln8 & 7) << 4);   // pre-swizzled src col

  const char* Ab = (const char*)A;
  const char* Bb = (const char*)B;

  // prologue: stage tile 0 into buf 0
#pragma unroll
  for (int c = 0; c < 4; ++c) {
    int r = wv * 32 + c * 8;                          // wave-uniform, r%8==0
    async16(Ab + (size_t)(m0 + r + ln8) * 2048 + scol, sm + r * 128);
  }
#pragma unroll
  for (int c = 0; c < BROWS / 32; ++c) {
    int r = wv * (BROWS / 4) + c * 8;
    async16(Bb + (size_t)(n0 + r + ln8) * 2048 + scol, sm + ABYTES + r * 128);
  }

  int kt2 = 128;                                      // byte offset of next k-tile
  for (int p = 0; p < 16; ++p) {
    asm volatile("s_waitcnt vmcnt(0)" ::: "memory");  // own DMA landed
    __builtin_amdgcn_s_barrier();                     // all waves done+landed
    __builtin_amdgcn_sched_barrier(0);
    if (p < 15) {                                     // stage t+1 -> other buf
      char* bas = sm + ((p + 1) & 1) * BUF;
#pragma unroll
      for (int c = 0; c < 4; ++c) {
        int r = wv * 32 + c * 8;
        async16(Ab + (size_t)(m0 + r + ln8) * 2048 + kt2 + scol, bas + r * 128);
      }
#pragma unroll
      for (int c = 0; c < BROWS / 32; ++c) {
        int r = wv * (BROWS / 4) + c * 8;
        async16(Bb + (size_t)(n0 + r + ln8) * 2048 + kt2 + scol,
                bas + ABYTES + r * 128);
      }
      kt2 += 128;
    }
    __builtin_amdgcn_sched_barrier(0);                // pin: DMA issued first
    const char* basA = sm + (p & 1) * BUF;
    const char* basB = basA + ABYTES;
#pragma unroll
    for (int ks = 0; ks < 2; ++ks) {
      bf16x8 af[4], bg[BROWS / 32];
#pragma unroll
      for (int i = 0; i < 4; ++i) {
        int row = wm * 64 + i * 16 + li;
        af[i] = *(const bf16x8*)(basA + row * 128 +
                                 ((ks * 64 + g * 16) ^ ((row & 7) << 4)));
      }
#pragma unroll
      for (int j = 0; j < BROWS / 32; ++j) {
        int row = wn * (BROWS / 2) + j * 16 + li;
        bg[j] = *(const bf16x8*)(basB + row * 128 +
                                 ((ks * 64 + g * 16) ^ ((row & 7) << 4)));
      }
#pragma unroll
      for (int i = 0; i < 4; ++i)
#pragma unroll
        for (int j = 0; j < BROWS / 32; ++j)
          acc[i][j] = MFMA(af[i], bg[j], acc[i][j]);
    }
  }
}

// ---------------------------------------------------------------------------
// 3-buffer counted-vmcnt pipeline (T3/T4): stage tile p+2 each phase, wait
// vmcnt(6) = drain own tile-p (6 DMAs) while p+1/p+2 stay in flight.
// BROWS=64: buffer = 16K(A) + 8K(B) = 24K; 3 bufs = 72K -> 2 blocks/CU.
__device__ __forceinline__ void gemm_pipe3(const bf16* __restrict__ A,
                                           const bf16* __restrict__ B,
                                           int m0, int n0,
                                           f32x4 acc[4][2],
                                           char* sm) {
  const int ABYTES = 128 * 128;
  const int BUF = ABYTES + 64 * 128;                  // 24576
  int tid = threadIdx.x, lane = tid & 63, wv = tid >> 6;
  int wm = wv & 1, wn = wv >> 1, g = lane >> 4, li = lane & 15;
  int ln8 = lane >> 3;
  int scol = ((lane & 7) << 4) ^ ((ln8 & 7) << 4);

  const char* Ab = (const char*)A;
  const char* Bb = (const char*)B;

#define STAGE3(kb, bas)                                                       \
  {                                                                           \
    _Pragma("unroll") for (int c = 0; c < 4; ++c) {                           \
      int r = wv * 32 + c * 8;                                                \
      async16(Ab + (size_t)(m0 + r + ln8) * 2048 + (kb) + scol,               \
              (bas) + r * 128);                                               \
    }                                                                         \
    _Pragma("unroll") for (int c = 0; c < 2; ++c) {                           \
      int r = wv * 16 + c * 8;                                                \
      async16(Bb + (size_t)(n0 + r + ln8) * 2048 + (kb) + scol,               \
              (bas) + ABYTES + r * 128);                                      \
    }                                                                         \
  }

#define COMPUTE3(basAq)                                                       \
  {                                                                           \
    const char* basA = (basAq);                                               \
    const char* basB = basA + ABYTES;                                         \
    _Pragma("unroll") for (int ks = 0; ks < 2; ++ks) {                        \
      bf16x8 af[4], bg[2];                                                    \
      _Pragma("unroll") for (int i = 0; i < 4; ++i) {                         \
        int row = wm * 64 + i * 16 + li;                                      \
        af[i] = *(const bf16x8*)(basA + row * 128 +                           \
                                 ((ks * 64 + g * 16) ^ ((row & 7) << 4)));    \
      }                                                                       \
      _Pragma("unroll") for (int j = 0; j < 2; ++j) {                         \
        int row = wn * 32 + j * 16 + li;                                      \
        bg[j] = *(const bf16x8*)(basB + row * 128 +                           \
                                 ((ks * 64 + g * 16) ^ ((row & 7) << 4)));    \
      }                                                                       \
      _Pragma("unroll") for (int i = 0; i < 4; ++i)                           \
        _Pragma("unroll") for (int j = 0; j < 2; ++j)                         \
          acc[i][j] = MFMA(af[i], bg[j], acc[i][j]);                          \
    }                                                                         \
  }

  // prologue: tiles 0 and 1
  STAGE3(0, sm);
  STAGE3(128, sm + BUF);

  for (int p = 0; p < 15; ++p) {
    asm volatile("s_waitcnt vmcnt(6)" ::: "memory");  // own tile-p landed
    __builtin_amdgcn_s_barrier();                     // everyone's tile-p in
    __builtin_amdgcn_sched_barrier(0);
    if (p < 14) {                                     // stage p+2
      int b3 = (p + 2) % 3;
      STAGE3((p + 2) * 128, sm + b3 * BUF);
    }
    __builtin_amdgcn_sched_barrier(0);                // pin: DMA issued first
    COMPUTE3(sm + (p % 3) * BUF);
  }
  // peeled last phase (p=15): only tile 15 outstanding
  asm volatile("s_waitcnt vmcnt(0)" ::: "memory");
  __builtin_amdgcn_s_barrier();
  __builtin_amdgcn_sched_barrier(0);
  COMPUTE3(sm + (15 % 3) * BUF);
#undef STAGE3
#undef COMPUTE3
}

// ---------------------------------------------------------------------------
// Legacy 2-barrier core, kept for the fp32-input fallback kernels only.
template <bool AF32, bool BF32>
__device__ __forceinline__ void gemm_core(const void* __restrict__ A,
                                          const void* __restrict__ B,
                                          int m0, int n0,
                                          f32x4 acc[4][4],
                                          bf16* Al, bf16* Bl) {
  const int K = 1024;
  int tid = threadIdx.x, lane = tid & 63, wv = tid >> 6;
  int wm = wv & 1, wn = wv >> 1, g = lane >> 4, li = lane & 15;
  int r8 = lane >> 3, c8 = lane & 7;

  for (int kt = 0; kt < K; kt += 64) {
    bf16x8 ta[4], tb[4];
#pragma unroll
    for (int i2 = 0; i2 < 4; ++i2) {
      int row = wv * 32 + i2 * 8 + r8;
      ta[i2] = ld8<AF32>(A, (size_t)(m0 + row) * K + kt + c8 * 8);
      tb[i2] = ld8<BF32>(B, (size_t)(n0 + row) * K + kt + c8 * 8);
    }
    __syncthreads();
#pragma unroll
    for (int i2 = 0; i2 < 4; ++i2) {
      int row = wv * 32 + i2 * 8 + r8;
      *(bf16x8*)&Al[row * 64 + c8 * 8] = ta[i2];
      *(bf16x8*)&Bl[row * 64 + c8 * 8] = tb[i2];
    }
    __syncthreads();
#pragma unroll
    for (int ks = 0; ks < 64; ks += 32) {
      bf16x8 af[4], bg[4];
#pragma unroll
      for (int i = 0; i < 4; ++i)
        af[i] = *(const bf16x8*)&Al[(wm * 64 + i * 16 + li) * 64 + ks + g * 8];
#pragma unroll
      for (int j = 0; j < 4; ++j)
        bg[j] = *(const bf16x8*)&Bl[(wn * 64 + j * 16 + li) * 64 + ks + g * 8];
#pragma unroll
      for (int i = 0; i < 4; ++i)
#pragma unroll
        for (int j = 0; j < 4; ++j)
          acc[i][j] = MFMA(af[i], bg[j], acc[i][j]);
    }
  }
}

// ---------------------------------------------------------------------------
__device__ __forceinline__ void epi_qk(f32x4 acc[4][4], int m0, int n0,
                                       const float* __restrict__ bias,
                                       bf16* __restrict__ qg, bf16* __restrict__ kg) {
  int lane = threadIdx.x & 63, wv = threadIdx.x >> 6;
  int wm = wv & 1, wn = wv >> 1, g = lane >> 4, li = lane & 15;
#pragma unroll
  for (int i = 0; i < 4; ++i) {
    int o = m0 + wm * 64 + i * 16 + g * 4;
    int s = o >> 10, h = (o >> 6) & 15, d = o & 63;
    float sc = s ? 1.0f : 0.125f * L2E;              // q in exp2 domain
    float b0 = bias[o], b1 = bias[o + 1], b2 = bias[o + 2], b3 = bias[o + 3];
    bf16* dstb = s ? kg : qg;
#pragma unroll
    for (int j = 0; j < 4; ++j) {
      int t = n0 + wn * 64 + j * 16 + li;
      int b = t >> 11, n = t & 2047;
      ushort4 pk;
      ((bf16*)&pk)[0] = (bf16)((acc[i][j][0] + b0) * sc);
      ((bf16*)&pk)[1] = (bf16)((acc[i][j][1] + b1) * sc);
      ((bf16*)&pk)[2] = (bf16)((acc[i][j][2] + b2) * sc);
      ((bf16*)&pk)[3] = (bf16)((acc[i][j][3] + b3) * sc);
      *(ushort4*)&dstb[(((size_t)b * 16 + h) * 2048 + n) * 64 + d] = pk;
    }
  }
}

// v epilogue for 64-wide n (acc[4][2]): m-side = token, n-side = ov.
__device__ __forceinline__ void epi_v2(f32x4 acc[4][2], int m0, int n0,
                                       const float* __restrict__ bias,
                                       bf16* __restrict__ vtg) {
  int lane = threadIdx.x & 63, wvv = threadIdx.x >> 6;
  int wm = wvv & 1, wn = wvv >> 1, g = lane >> 4, li = lane & 15;
#pragma unroll
  for (int i = 0; i < 4; ++i) {
    int t = m0 + wm * 64 + i * 16 + g * 4;           // 4 consecutive tokens
    int b = t >> 11, n = t & 2047;
#pragma unroll
    for (int j = 0; j < 2; ++j) {
      int ov = n0 + wn * 32 + j * 16 + li;
      int h = ov >> 6, d = ov & 63;
      float bv = bias[ov];
      ushort4 pk;
      ((bf16*)&pk)[0] = (bf16)(acc[i][j][0] + bv);
      ((bf16*)&pk)[1] = (bf16)(acc[i][j][1] + bv);
      ((bf16*)&pk)[2] = (bf16)(acc[i][j][2] + bv);
      ((bf16*)&pk)[3] = (bf16)(acc[i][j][3] + bv);
      *(ushort4*)&vtg[(((size_t)b * 16 + h) * 64 + d) * 2048 + n] = pk;
    }
  }
}

// legacy full-width v epilogue (fp32 fallback path)
__device__ __forceinline__ void epi_v(f32x4 acc[4][4], int m0, int n0,
                                      const float* __restrict__ bias,
                                      bf16* __restrict__ vtg) {
  int lane = threadIdx.x & 63, wvv = threadIdx.x >> 6;
  int wm = wvv & 1, wn = wvv >> 1, g = lane >> 4, li = lane & 15;
#pragma unroll
  for (int i = 0; i < 4; ++i) {
    int t = m0 + wm * 64 + i * 16 + g * 4;           // 4 consecutive tokens
    int b = t >> 11, n = t & 2047;
#pragma unroll
    for (int j = 0; j < 4; ++j) {
      int ov = n0 + wn * 64 + j * 16 + li;
      int h = ov >> 6, d = ov & 63;
      float bv = bias[ov];
      ushort4 pk;
      ((bf16*)&pk)[0] = (bf16)(acc[i][j][0] + bv);
      ((bf16*)&pk)[1] = (bf16)(acc[i][j][1] + bv);
      ((bf16*)&pk)[2] = (bf16)(acc[i][j][2] + bv);
      ((bf16*)&pk)[3] = (bf16)(acc[i][j][3] + bv);
      *(ushort4*)&vtg[(((size_t)b * 16 + h) * 64 + d) * 2048 + n] = pk;
    }
  }
}

// Fused QKV gemm (bf16 inputs): blocks [0,512) = qk (128x128 tiles),
// [512,1024) = v (128tok x 64ov half-tiles -> full-width backfill window).
// XCD maps: qk: xcd=bid&7 owns 4 token-panels x 16 m-panels.
//           v:  xcd=vb&7 owns 4 token-panels x 16 ov-panels (1MB xb + 2MB wv).
__global__ __launch_bounds__(256) void gemm_qkv(const bf16* __restrict__ xb,
                                                const bf16* __restrict__ qwb,
                                                const float* __restrict__ bias,
                                                bf16* __restrict__ qg,
                                                bf16* __restrict__ kg,
                                                bf16* __restrict__ vtg) {
  __shared__ __align__(16) char sm[65536];           // 2 buf x (A 16K + B 16K)
  int bid = blockIdx.x;
  if (bid < 512) {
    f32x4 acc[4][4];
#pragma unroll
    for (int i = 0; i < 4; ++i)
#pragma unroll
      for (int j = 0; j < 4; ++j) acc[i][j] = (f32x4){0.f, 0.f, 0.f, 0.f};
    int xcd = bid & 7, local = bid >> 3;             // local in [0,64)
    int m0 = (local >> 2) * 128;                     // 16 m-panels
    int n0 = (xcd * 4 + (local & 3)) * 128;          // 32 n-panels, 4/XCD
    gemm_pipe<128>(qwb, xb, m0, n0, acc, sm);
    epi_qk(acc, m0, n0, bias, qg, kg);
  } else {
    f32x4 acc[4][2];
#pragma unroll
    for (int i = 0; i < 4; ++i)
#pragma unroll
      for (int j = 0; j < 2; ++j) acc[i][j] = (f32x4){0.f, 0.f, 0.f, 0.f};
    int vb = bid - 512;                              // [0,512)
    int xcd = vb & 7, local = vb >> 3;               // local in [0,64)
    int m0 = (xcd * 4 + (local & 3)) * 128;          // 32 token-panels, 4/XCD
    int n0 = (local >> 2) * 64;                      // 16 ov-panels
    gemm_pipe<64>(xb, qwb + (size_t)2048 * 1024, m0, n0, acc, sm);
    epi_v2(acc, m0, n0, bias + 2048, vtg);
  }
}

// Fallback fp32-input kernels (ws too small to pre-convert)
__global__ __launch_bounds__(256) void gemm_qk_f(const float* __restrict__ x,
                                                 const float* __restrict__ w,
                                                 const float* __restrict__ bias,
                                                 bf16* __restrict__ qg,
                                                 bf16* __restrict__ kg) {
  __shared__ bf16 Al[128 * 64], Bl[128 * 64];
  f32x4 acc[4][4];
#pragma unroll
  for (int i = 0; i < 4; ++i)
#pragma unroll
    for (int j = 0; j < 4; ++j) acc[i][j] = (f32x4){0.f, 0.f, 0.f, 0.f};
  int m0 = blockIdx.y * 128, n0 = blockIdx.x * 128;
  gemm_core<true, true>(w, x, m0, n0, acc, Al, Bl);
  epi_qk(acc, m0, n0, bias, qg, kg);
}
__global__ __launch_bounds__(256) void gemm_v_f(const float* __restrict__ x,
                                                const float* __restrict__ wv_,
                                                const float* __restrict__ bias,
                                                bf16* __restrict__ vtg) {
  __shared__ bf16 Al[128 * 64], Bl[128 * 64];
  f32x4 acc[4][4];
#pragma unroll
  for (int i = 0; i < 4; ++i)
#pragma unroll
    for (int j = 0; j < 4; ++j) acc[i][j] = (f32x4){0.f, 0.f, 0.f, 0.f};
  int m0 = blockIdx.y * 128, n0 = blockIdx.x * 128;
  gemm_core<true, true>(x, wv_, m0, n0, acc, Al, Bl);
  epi_v(acc, m0, n0, bias, vtg);
}
__global__ __launch_bounds__(256) void mask_bits(const int* __restrict__ mask,
                                                 unsigned long long* __restrict__ mbg) {
  int row = blockIdx.x, lane = threadIdx.x & 63, wv = threadIdx.x >> 6;
  const int* mrow = mask + (size_t)row * 2048;
#pragma unroll
  for (int i = 0; i < 8; ++i) {
    int w = wv * 8 + i;
    unsigned long long bal = __ballot(mrow[w * 64 + lane] != 0);
    if (lane == 0) mbg[(size_t)row * 32 + w] = bal;
  }
}

// ---------------------------------------------------------------------------
// Flash attention, 32x32x16, 8 waves = 2 n-groups x 4 q-waves, async16-direct
// double-buffered K/V, one raw barrier per phase, setprio. R17: persistent
// zero16 C-operand for accS chains (no per-phase zero-init VALU).
__global__ __launch_bounds__(512, 4) void flash_attn(
    const bf16* __restrict__ qg, const bf16* __restrict__ kg,
    const bf16* __restrict__ vtg, const unsigned long long* __restrict__ mbg,
    bf16* __restrict__ G) {
  // [0,64K): 2 grp x 2 buf x (K 8K | V 8K). Post-loop overlay: Ocomb = wg*8K.
  // [64K, 64K+512): lbuf.
  __shared__ __align__(16) char smem[66048];

  int tid = threadIdx.x, lane = tid & 63, wv8 = tid >> 6;
  int grp = wv8 >> 2, wg = wv8 & 3;
  int cl = lane & 31, hi = lane >> 5;
  // XCD swizzle: blk = (bh&7) + 8*(q + 16*(bh>>3)) -> xcd = bh&7; 4 heads +
  // their 16 q-blocks per XCD (K/V working set 2MB < 4MB L2).
  int sblk = blockIdx.x;
  int rest = sblk >> 3;
  int bh = ((rest >> 4) << 3) | (sblk & 7);
  int q0 = (rest & 15) * 128;
  int b = bh >> 4;

  const bf16* qbase = qg + (size_t)bh * 2048 * 64;
  const char* kgc = (const char*)(kg + (size_t)bh * 2048 * 64);
  const char* vgc = (const char*)(vtg + (size_t)bh * 64 * 2048);

  int qrow = q0 + wg * 32 + cl;
  bf16x8 qf[4];                          // Q B-frags: row q=cl, k = kd*16+hi*8
#pragma unroll
  for (int kd = 0; kd < 4; ++kd)
    qf[kd] = *(const bf16x8*)&qbase[(size_t)qrow * 64 + kd * 16 + hi * 8];

  // pre-swizzled per-lane staging source offsets (swizzle granule = 16B:
  // LDS linear slot (row, c) <- global col c^((row&7)); read undoes the XOR)
  int ln8 = lane >> 3;
  int kcol = ((lane & 7) << 4) ^ ((ln8 & 7) << 4);
  int koff = (grp * 64 + wg * 16 + ln8) * 128 + kcol;    // += 16384/phase
  int voff = (wg * 16 + ln8) * 4096 + grp * 128 + kcol;  // += 256/phase
  const char* mB = (const char*)mbg;
  unsigned moff = (unsigned)(((b * 2048 + qrow) * 32 + grp) * 8);  // += 16
  int ldsw = wg * 2048;                  // wave-uniform LDS chunk

  // prologue: stage this group's tile 0 into buf0
  {
    char* kl = smem + grp * 32768;
    char* vl = kl + 8192;
    async16(kgc + koff, kl + ldsw);
    async16(kgc + koff + 1024, kl + ldsw + 1024);
    async16(vgc + voff, vl + ldsw);
    async16(vgc + voff + 32768, vl + ldsw + 1024);
  }
  unsigned long long mw_next = *(const unsigned long long*)(mB + moff);

  f32x16 accO0, accO1, zero16;
#pragma unroll
  for (int e = 0; e < 16; ++e) { accO0[e] = 0.f; accO1[e] = 0.f; zero16[e] = 0.f; }
  float lsum = 0.f;
  int swr = (cl & 7) << 4;

  for (int t = 0; t < 16; ++t) {
    // own staging landed -> barrier -> (everyone's staging landed AND all
    // prior-phase reads of the other buffer are done)
    asm volatile("s_waitcnt vmcnt(0)" ::: "memory");
    __builtin_amdgcn_s_barrier();
    __builtin_amdgcn_sched_barrier(0);
    unsigned long long mwc = mw_next;
    if (t < 15) {                        // stage next tile into other buffer
      koff += 16384; voff += 256; moff += 16;
      char* kl = smem + grp * 32768 + (((t + 1) & 1) << 14);
      char* vl = kl + 8192;
      async16(kgc + koff, kl + ldsw);
      async16(kgc + koff + 1024, kl + ldsw + 1024);
      async16(vgc + voff, vl + ldsw);
      async16(vgc + voff + 32768, vl + ldsw + 1024);
      mw_next = *(const unsigned long long*)(mB + moff);
    }
    __builtin_amdgcn_sched_barrier(0);   // pin: DMA issued before compute
    const char* Kl = smem + grp * 32768 + ((t & 1) << 14);
    const char* Vl = Kl + 8192;

    // S^T = K Q^T (log2 domain): accS0 = n 0..31, accS1 = n 32..63.
    // First MFMA uses persistent zero16 as C (D != C legal) -> no re-init.
    f32x16 accS0, accS1;
    __builtin_amdgcn_s_setprio(1);
    {
      int cb = (hi * 16) ^ swr;          // kd = 0
      bf16x8 kf0 = *(const bf16x8*)(Kl + cl * 128 + cb);
      bf16x8 kf1 = *(const bf16x8*)(Kl + (32 + cl) * 128 + cb);
      accS0 = MFMA32(kf0, qf[0], zero16);
      accS1 = MFMA32(kf1, qf[0], zero16);
    }
#pragma unroll
    for (int kd = 1; kd < 4; ++kd) {
      int cb = (kd * 32 + hi * 16) ^ swr;
      bf16x8 kf0 = *(const bf16x8*)(Kl + cl * 128 + cb);
      bf16x8 kf1 = *(const bf16x8*)(Kl + (32 + cl) * 128 + cb);
      accS0 = MFMA32(kf0, qf[kd], accS0);
      accS1 = MFMA32(kf1, qf[kd], accS1);
    }
    __builtin_amdgcn_s_setprio(0);

    // p = mask * exp2(s): sbfe sign-mask + and; pack pairs via cvt_pk
    unsigned dw[16];
#pragma unroll
    for (int nb = 0; nb < 2; ++nb) {
      unsigned mql = (unsigned)(mwc >> (nb * 32));
#pragma unroll
      for (int j = 0; j < 4; ++j) {
        int pos = j * 8 + hi * 4;
        float p0 = EXP2(nb ? accS1[4 * j + 0] : accS0[4 * j + 0]);
        float p1 = EXP2(nb ? accS1[4 * j + 1] : accS0[4 * j + 1]);
        float p2 = EXP2(nb ? accS1[4 * j + 2] : accS0[4 * j + 2]);
        float p3 = EXP2(nb ? accS1[4 * j + 3] : accS0[4 * j + 3]);
        p0 = maskf(p0, mql, pos);     p1 = maskf(p1, mql, pos + 1);
        p2 = maskf(p2, mql, pos + 2); p3 = maskf(p3, mql, pos + 3);
        lsum += (p0 + p1) + (p2 + p3);
        dw[nb * 8 + 2 * j]     = cvt_pk_bf16(p0, p1);
        dw[nb * 8 + 2 * j + 1] = cvt_pk_bf16(p2, p3);
      }
    }

    // O^T += V^T P^T; B-frag assembled from own+partner dwords (lane l<->l+32)
    __builtin_amdgcn_s_setprio(1);
#pragma unroll
    for (int kk = 0; kk < 4; ++kk) {
      union { unsigned u[4]; bf16x8 v; } pa;
      lane32_swap(dw[4 * kk], dw[4 * kk + 2], pa.u[0], pa.u[2], hi);
      lane32_swap(dw[4 * kk + 1], dw[4 * kk + 3], pa.u[1], pa.u[3], hi);
      int cb = (kk * 32 + hi * 16) ^ swr;
      bf16x8 vf0 = *(const bf16x8*)(Vl + cl * 128 + cb);
      bf16x8 vf1 = *(const bf16x8*)(Vl + (32 + cl) * 128 + cb);
      accO0 = MFMA32(vf0, pa.v, accO0);
      accO1 = MFMA32(vf1, pa.v, accO1);
    }
    __builtin_amdgcn_s_setprio(0);
  }

  // partner lane (l^32) holds the other half of each q-row's p values
  float ltot = lsum + __shfl_xor(lsum, 32);

  // ---- cross-group combine (tile buffers dead -> realias) ----
  __syncthreads();
  float* oc = (float*)(smem + wg * 8192);  // [32 q][64 d] f32, XOR-swizzled
  float* lbuf = (float*)(smem + 65536);
  int osw = (cl & 7) << 4;
  if (grp == 1) {
#pragma unroll
    for (int j = 0; j < 4; ++j) {
      f32x4 qa, qb;
#pragma unroll
      for (int r = 0; r < 4; ++r) { qa[r] = accO0[4 * j + r]; qb[r] = accO1[4 * j + r]; }
      int dby = j * 32 + hi * 16;
      *(f32x4*)((char*)oc + cl * 256 + (dby ^ osw)) = qa;
      *(f32x4*)((char*)oc + cl * 256 + ((dby + 128) ^ osw)) = qb;
    }
    if (hi == 0) lbuf[wg * 32 + cl] = ltot;
  }
  __syncthreads();
  if (grp == 1) return;

  float lt2 = ltot + lbuf[wg * 32 + cl];
  float inv = 1.0f / fmaxf(lt2, 1e-37f);
#pragma unroll
  for (int j = 0; j < 4; ++j) {
    int dby = j * 32 + hi * 16;
    f32x4 qa = *(const f32x4*)((char*)oc + cl * 256 + (dby ^ osw));
    f32x4 qb = *(const f32x4*)((char*)oc + cl * 256 + ((dby + 128) ^ osw));
#pragma unroll
    for (int r = 0; r < 4; ++r) {
      accO0[4 * j + r] = (accO0[4 * j + r] + qa[r]) * inv;
      accO1[4 * j + r] = (accO1[4 * j + r] + qb[r]) * inv;
    }
  }

  // epilogue transpose, wave-private (same-wave LDS ops are in-order ->
  // overlaying the just-read oc region is safe)
  bf16* ow = (bf16*)(smem + wg * 8192);
#pragma unroll
  for (int db = 0; db < 2; ++db) {
#pragma unroll
    for (int jq = 0; jq < 4; ++jq) {
      ushort4 pk;
      ((bf16*)&pk)[0] = (bf16)(db ? accO1[4 * jq + 0] : accO0[4 * jq + 0]);
      ((bf16*)&pk)[1] = (bf16)(db ? accO1[4 * jq + 1] : accO0[4 * jq + 1]);
      ((bf16*)&pk)[2] = (bf16)(db ? accO1[4 * jq + 2] : accO0[4 * jq + 2]);
      ((bf16*)&pk)[3] = (bf16)(db ? accO1[4 * jq + 3] : accO0[4 * jq + 3]);
      int dbase = db * 32 + jq * 8 + hi * 4;
      *(ushort4*)&ow[cl * 72 + dbase] = pk;
    }
  }

  int ql = lane >> 1, part = lane & 1;
  size_t tok = (size_t)b * 2048 + q0 + wg * 32 + ql;
  bf16* dst = G + tok * 1024 + (bh & 15) * 64 + part * 32;
  const bf16* src = &ow[ql * 72 + part * 32];
#pragma unroll
  for (int j = 0; j < 4; ++j)
    *(bf16x8*)&dst[j * 8] = *(const bf16x8*)&src[j * 8];
}

// ---------------------------------------------------------------------------
// Proj (pre path): D[ch][token], tile 128x64, 3-buffer counted-vmcnt pipeline.
__global__ __launch_bounds__(256) void gemm_proj_n(const bf16* __restrict__ G,
                                                   const bf16* __restrict__ w,
                                                   const float* __restrict__ bias,
                                                   float* __restrict__ out) {
  __shared__ __align__(16) char sm[73728];           // 3 buf x (A 16K + B 8K)
  int lane = threadIdx.x & 63, wv = threadIdx.x >> 6;
  int wm = wv & 1, wn = wv >> 1, g = lane >> 4, li = lane & 15;
  int m0 = blockIdx.y * 128, n0 = blockIdx.x * 64;

  f32x4 acc[4][2];
#pragma unroll
  for (int i = 0; i < 4; ++i)
#pragma unroll
    for (int j = 0; j < 2; ++j) acc[i][j] = (f32x4){0.f, 0.f, 0.f, 0.f};

  gemm_pipe3(w, G, m0, n0, acc, sm);

#pragma unroll
  for (int i = 0; i < 4; ++i) {
    int ch = m0 + wm * 64 + i * 16 + g * 4;
    float b0 = bias[ch], b1 = bias[ch + 1], b2 = bias[ch + 2], b3 = bias[ch + 3];
#pragma unroll
    for (int j = 0; j < 2; ++j) {
      int t = n0 + wn * 32 + j * 16 + li;
      float4 pk = make_float4(acc[i][j][0] + b0, acc[i][j][1] + b1,
                              acc[i][j][2] + b2, acc[i][j][3] + b3);
      *(float4*)&out[(size_t)t * 1024 + ch] = pk;
    }
  }
}

// Fallback proj (fp32 weights)
__global__ __launch_bounds__(256) void gemm_proj_f(const bf16* __restrict__ G,
                                                   const float* __restrict__ w,
                                                   const float* __restrict__ bias,
                                                   float* __restrict__ out) {
  __shared__ bf16 Al[128 * 64], Bl[128 * 64];
  f32x4 acc[4][4];
#pragma unroll
  for (int i = 0; i < 4; ++i)
#pragma unroll
    for (int j = 0; j < 4; ++j) acc[i][j] = (f32x4){0.f, 0.f, 0.f, 0.f};
  int m0 = blockIdx.y * 128, n0 = blockIdx.x * 128;
  gemm_core<true, false>(w, G, m0, n0, acc, Al, Bl);

  int lane = threadIdx.x & 63, wv = threadIdx.x >> 6;
  int wm = wv & 1, wn = wv >> 1, g = lane >> 4, li = lane & 15;
#pragma unroll
  for (int i = 0; i < 4; ++i) {
    int ch = m0 + wm * 64 + i * 16 + g * 4;
    float b0 = bias[ch], b1 = bias[ch + 1], b2 = bias[ch + 2], b3 = bias[ch + 3];
#pragma unroll
    for (int j = 0; j < 4; ++j) {
      int t = n0 + wn * 64 + j * 16 + li;
      float4 pk = make_float4(acc[i][j][0] + b0, acc[i][j][1] + b1,
                              acc[i][j][2] + b2, acc[i][j][3] + b3);
      *(float4*)&out[(size_t)t * 1024 + ch] = pk;
    }
  }
}

// ---------------------------------------------------------------------------
extern "C" void kernel_launch(void* const* d_in, const int* in_sizes, int n_in,
                              void* d_out, int out_size, void* d_ws, size_t ws_size,
                              hipStream_t stream) {
  const float* x      = (const float*)d_in[0];   // (2,2048,1024)
  const float* qkv_w  = (const float*)d_in[1];   // (3072,1024)
  const float* qkv_b  = (const float*)d_in[2];   // (3072,)
  const float* proj_w = (const float*)d_in[3];   // (1024,1024)
  const float* proj_b = (const float*)d_in[4];   // (1024,)
  // d_in[5] physics_bias: softmax-invariant, unused.
  const int* mask     = (const int*)d_in[6];     // (2,1,2048,2048) int32
  float* out = (float*)d_out;

  const size_t MB = (size_t)1 << 20;
  char* ws = (char*)d_ws;
  bf16* qg  = (bf16*)(ws);                 // 8 MB  [b][h][n][d]
  bf16* kg  = (bf16*)(ws + 8 * MB);        // 8 MB  [b][h][n][d]
  bf16* vtg = (bf16*)(ws + 16 * MB);       // 8 MB  [b][h][d][n]
  bf16* xb  = (bf16*)(ws + 24 * MB);       // 8 MB  (shared: xb dead before G written)
  bf16* G   = (bf16*)(ws + 24 * MB);       // 8 MB  [token][1024]
  unsigned long long* mbg = (unsigned long long*)(ws + 32 * MB);  // 1 MB
  bf16* qwb = (bf16*)(ws + 33 * MB);       // 6 MB
  bf16* pwb = (bf16*)(ws + 39 * MB);       // 2 MB
  bool pre = ws_size >= 41 * MB;           // constant across calls (graph-safe)

  if (pre) {
    prep<<<dim3(8192), dim3(256), 0, stream>>>(mask, mbg, x, xb, qkv_w, qwb,
                                               proj_w, pwb);
    gemm_qkv<<<dim3(1024), dim3(256), 0, stream>>>(xb, qwb, qkv_b, qg, kg, vtg);
  } else {
    mask_bits<<<dim3(4096), dim3(256), 0, stream>>>(mask, mbg);
    gemm_qk_f<<<dim3(32, 16), dim3(256), 0, stream>>>(x, qkv_w, qkv_b, qg, kg);
    gemm_v_f<<<dim3(8, 32), dim3(256), 0, stream>>>(
        x, qkv_w + (size_t)2048 * 1024, qkv_b + 2048, vtg);
  }

  flash_attn<<<dim3(512), dim3(512), 0, stream>>>(qg, kg, vtg, mbg, G);

  if (pre)
    gemm_proj_n<<<dim3(64, 8), dim3(256), 0, stream>>>(G, pwb, proj_b, out);
  else
    gemm_proj_f<<<dim3(32, 8), dim3(256), 0, stream>>>(G, proj_w, proj_b, out);
}